// Round 8
// baseline (309.912 us; speedup 1.0000x reference)
//
#include <hip/hip_runtime.h>
#include <stdint.h>

// ScoreMatching: B=2048, D=64, H=512.
// out[b] = 0.5*||s_b||^2 + tr(W4 M3 W3 M2 W2 M1 W1)_b
// div_b = sum_{i,d} m2[i] * C[i,d] * G[i,d]
//   C = W2 @ (M1 .* W1)      [512 x 64]   A-frag = W2 rows,  B-frag = masked W1T rows
//   G = W3^T @ (M3 .* W4^T)  [512 x 64]   A-frag = W3T rows, B-frag = masked W4 rows
// R12 changes:
//  - div: REVERT to v5 (R6, 146us). v6's global B-loads coupled L1/L2 latency
//    into the per-kc vmcnt wait (156us, MfmaUtil 38.7 vs 41).
//  - forward v6: the invariant ~105us across all variants is the per-k
//    UNIFORM-ADDRESS ds_read_b128 (16 waves x 512 x ~12cyc = ~98K cyc/CU per
//    big layer = ~80us for layers 2+3). Replace with lane-distributed h +
//    v_readlane broadcast: per 64-k stripe one coalesced per-lane b128 read
//    (8/thread/layer instead of 512 broadcast reads/wave), then
//    readlane(hreg, l) feeds SGPR-operand FMAs -- zero LDS pipe in the k-loop.
//    Thread t still owns unit t: ballot masks and FMA order bit-identical.
//    Layer 4 converted identically (256 uniform b32 reads/wave had same cost).

typedef __attribute__((ext_vector_type(8))) short short8;
typedef __attribute__((ext_vector_type(4))) float f32x4;

union U16x8 {
  uint4 u;
  short8 s;
};

__device__ __forceinline__ uint16_t f2bf(float f) {
  uint32_t u = __float_as_uint(f);
  uint32_t lsb = (u >> 16) & 1u;
  u += 0x7FFFu + lsb;  // round-to-nearest-even
  return (uint16_t)(u >> 16);
}

// async global->LDS, 16B per lane: lane's data lands at lds_base + lane*16.
__device__ __forceinline__ void lds_load16(const uint4* gsrc, uint4* ldst) {
  __builtin_amdgcn_global_load_lds(
      (const __attribute__((address_space(1))) void*)gsrc,
      (__attribute__((address_space(3))) void*)ldst, 16, 0, 0);
}

// lane-broadcast: v_readlane_b32 (lane index is wave-uniform, runtime OK)
__device__ __forceinline__ float rlane(float v, int l) {
  return __int_as_float(__builtin_amdgcn_readlane(__float_as_int(v), l));
}

// ---------------- convert: build swizzled bf16 fragments + fp32 transposes ----------------
// Fragment order (16x16x32 bf16 MFMA): lane = quad*16 + l15 holds 8 contiguous
// bf16 = 16 B; A-frag element (m=l15, k=quad*8+j); B-frag (n=l15, k=quad*8+j).
// A2swz[((r16*16 + kc)*64 + lane)*8 + j] = W2 [r16*16+l15][kc*32+quad*8+j]
// A3swz[  same index                   ] = W3T[r16*16+l15][kc*32+quad*8+j]
// B1swz[((kc*4 + jt)*64 + lane)*8 + j]  = W1T[jt*16+l15 ][kc*32+quad*8+j]
// B4swz[  same index                 ]  = W4 [jt*16+l15 ][kc*32+quad*8+j]
__global__ __launch_bounds__(256) void convert_kernel(
    const float* __restrict__ W1, const float* __restrict__ W2,
    const float* __restrict__ W3, const float* __restrict__ W4,
    uint16_t* __restrict__ A2swz, uint16_t* __restrict__ A3swz,
    uint16_t* __restrict__ B1swz, uint16_t* __restrict__ B4swz,
    float* __restrict__ W2Tf, float* __restrict__ W3Tf,
    float* __restrict__ W1Tf, float* __restrict__ W4Tf) {
  const int i = blockIdx.x * 256 + threadIdx.x;
  if (i < 262144) {  // A2swz
    const int e = i;
    const int f = e >> 3, j = e & 7;
    const int lane = f & 63, fk = f >> 6;
    const int kc = fk & 15, r16 = fk >> 4;
    const int l15 = lane & 15, quad = lane >> 4;
    const int row = r16 * 16 + l15, col = kc * 32 + quad * 8 + j;
    A2swz[e] = f2bf(W2[row * 512 + col]);
  } else if (i < 524288) {  // A3swz (= W3 transposed)
    const int e = i - 262144;
    const int f = e >> 3, j = e & 7;
    const int lane = f & 63, fk = f >> 6;
    const int kc = fk & 15, r16 = fk >> 4;
    const int l15 = lane & 15, quad = lane >> 4;
    const int row = r16 * 16 + l15, col = kc * 32 + quad * 8 + j;
    A3swz[e] = f2bf(W3[col * 512 + row]);
  } else if (i < 557056) {  // B1swz (= W1 transposed)
    const int e = i - 524288;
    const int f = e >> 3, j = e & 7;
    const int lane = f & 63, fk = f >> 6;
    const int kc = fk >> 2, jt = fk & 3;
    const int l15 = lane & 15, quad = lane >> 4;
    const int d = jt * 16 + l15, col = kc * 32 + quad * 8 + j;
    B1swz[e] = f2bf(W1[col * 64 + d]);
  } else if (i < 589824) {  // B4swz (= W4 row-major)
    const int e = i - 557056;
    const int f = e >> 3, j = e & 7;
    const int lane = f & 63, fk = f >> 6;
    const int kc = fk >> 2, jt = fk & 3;
    const int l15 = lane & 15, quad = lane >> 4;
    const int d = jt * 16 + l15, col = kc * 32 + quad * 8 + j;
    B4swz[e] = f2bf(W4[d * 512 + col]);
  } else if (i < 851968) {  // W2Tf [k][j]
    const int e = i - 589824;
    const int k = e >> 9, jj = e & 511;
    W2Tf[e] = W2[jj * 512 + k];
  } else if (i < 1114112) {  // W3Tf [k][j]
    const int e = i - 851968;
    const int k = e >> 9, jj = e & 511;
    W3Tf[e] = W3[jj * 512 + k];
  } else if (i < 1146880) {  // W1Tf [k][j], k<64
    const int e = i - 1114112;
    const int k = e >> 9, jj = e & 511;
    W1Tf[e] = W1[jj * 64 + k];
  } else if (i < 1179648) {  // W4Tf [k][d]
    const int e = i - 1146880;
    const int k = e >> 6, d = e & 63;
    W4Tf[e] = W4[d * 512 + k];
  }
}

// ---------------- forward v6 (fp32): readlane h-broadcast, zero in-loop LDS ----------------
// 512 blocks x 512 threads (8 waves, 2 blocks/CU); 4 samples/block.
// Thread t owns unit j=t. Per 64-k stripe r: one per-lane coalesced b128 read
// hcur = h[r*64+lane][0..3]; per k: 4 readlane + 4 FMA (SGPR h operand) + one
// prefetched coalesced 4B w-load. W double-buffered 8-deep, crossing stripes.
// Mask: wave w covers units w*64..+63 -> __ballot = words 2w, 2w+1. No atomics.
__device__ __forceinline__ void relu_store_mask4(
    float acc[4], float (*hdst)[4], uint32_t* __restrict__ mbase,
    int t, int lane, int wv) {
#pragma unroll
  for (int s = 0; s < 4; ++s) {
    const unsigned long long bal = __ballot(acc[s] > 0.f);
    if (lane == 0) {
      uint2 w2;
      w2.x = (uint32_t)bal;
      w2.y = (uint32_t)(bal >> 32);
      *(uint2*)(mbase + (size_t)s * 16 + 2 * wv) = w2;
    }
  }
  float4 r;
  r.x = acc[0] > 0.f ? acc[0] : 0.f;
  r.y = acc[1] > 0.f ? acc[1] : 0.f;
  r.z = acc[2] > 0.f ? acc[2] : 0.f;
  r.w = acc[3] > 0.f ? acc[3] : 0.f;
  *(float4*)&hdst[t][0] = r;
}

template <int R>  // K = R*64
__device__ __forceinline__ void fwd_layer_rl(
    const float* __restrict__ WT, const float* __restrict__ bias,
    const float (* __restrict__ src)[4], float (* __restrict__ dst)[4],
    uint32_t* __restrict__ mbase, int t, int lane, int wv) {
  const float bj = bias[t];
  float acc[4] = {bj, bj, bj, bj};
  const float* Wp = WT + t;
  float wA[8], wB[8];
#pragma unroll
  for (int j = 0; j < 8; ++j) wA[j] = Wp[(size_t)j * 512];
  float4 h0 = *(const float4*)&src[lane][0];
  float4 h1;
#pragma unroll
  for (int r = 0; r < R; ++r) {
    const int kr = r * 64;
    // prefetch next stripe's h into the other slot (static alternation)
    if (r + 1 < R) {
      if (r & 1) h0 = *(const float4*)&src[kr + 64 + lane][0];
      else       h1 = *(const float4*)&src[kr + 64 + lane][0];
    }
    const float4 hc = (r & 1) ? h1 : h0;
#pragma unroll 1
    for (int lb = 0; lb < 64; lb += 16) {
#pragma unroll
      for (int j = 0; j < 8; ++j) wB[j] = Wp[(size_t)(kr + lb + 8 + j) * 512];
#pragma unroll
      for (int j = 0; j < 8; ++j) {
        const int l = lb + j;
        const float w = wA[j];
        acc[0] = fmaf(w, rlane(hc.x, l), acc[0]);
        acc[1] = fmaf(w, rlane(hc.y, l), acc[1]);
        acc[2] = fmaf(w, rlane(hc.z, l), acc[2]);
        acc[3] = fmaf(w, rlane(hc.w, l), acc[3]);
      }
      // reload wA for the NEXT 8 k's (crosses into next stripe seamlessly)
      if (kr + lb + 16 < R * 64) {
#pragma unroll
        for (int j = 0; j < 8; ++j) wA[j] = Wp[(size_t)(kr + lb + 16 + j) * 512];
      }
#pragma unroll
      for (int j = 0; j < 8; ++j) {
        const int l = lb + 8 + j;
        const float w = wB[j];
        acc[0] = fmaf(w, rlane(hc.x, l), acc[0]);
        acc[1] = fmaf(w, rlane(hc.y, l), acc[1]);
        acc[2] = fmaf(w, rlane(hc.z, l), acc[2]);
        acc[3] = fmaf(w, rlane(hc.w, l), acc[3]);
      }
    }
  }
  relu_store_mask4(acc, dst, mbase, t, lane, wv);
}

__global__ __launch_bounds__(512) void forward_kernel(
    const float* __restrict__ x,
    const float* __restrict__ W1Tf, const float* __restrict__ b1,
    const float* __restrict__ W2Tf, const float* __restrict__ b2,
    const float* __restrict__ W3Tf, const float* __restrict__ b3,
    const float* __restrict__ W4Tf, const float* __restrict__ b4,
    uint32_t* __restrict__ m1p, uint32_t* __restrict__ m2p,
    uint32_t* __restrict__ m3p, float* __restrict__ out) {
  __shared__ float xs[64][4];   // [k][sample]
  __shared__ float hA[512][4];  // [unit][sample]
  __shared__ float hB[512][4];
  __shared__ float p4[4][2][64];  // layer-4 partials [sample][k-half][d]
  const int t = threadIdx.x;
  const int lane = t & 63, wv = t >> 6;
  const int b0 = blockIdx.x * 4;

  if (t < 256) {
    const int k = t >> 2, s = t & 3;  // 256 threads cover 4 samples x 64 k
    xs[k][s] = x[(size_t)(b0 + s) * 64 + k];
  }
  __syncthreads();

  fwd_layer_rl<1>(W1Tf, b1, xs, hA, m1p + (size_t)b0 * 16, t, lane, wv);
  __syncthreads();
  fwd_layer_rl<8>(W2Tf, b2, hA, hB, m2p + (size_t)b0 * 16, t, lane, wv);
  __syncthreads();
  fwd_layer_rl<8>(W3Tf, b3, hB, hA, m3p + (size_t)b0 * 16, t, lane, wv);
  __syncthreads();

  // ---- layer 4 (K=512, D=64) + 0.5*||s||^2 : 8 waves, k-halves, readlane ----
  {
    const int s = wv & 3, hh = wv >> 2, d = lane;
    const int k0 = hh * 256;
    const float* Wp = W4Tf + (size_t)k0 * 64 + d;
    // per-lane h preload: hr[r] = hA[k0 + r*64 + lane][s], r = 0..3
    const float hr0 = hA[k0 + 0 * 64 + lane][s];
    const float hr1 = hA[k0 + 1 * 64 + lane][s];
    const float hr2 = hA[k0 + 2 * 64 + lane][s];
    const float hr3 = hA[k0 + 3 * 64 + lane][s];
    float ap[4] = {0.f, 0.f, 0.f, 0.f};
    float wA[8], wB[8];
#pragma unroll
    for (int j = 0; j < 8; ++j) wA[j] = Wp[(size_t)j * 64];
#pragma unroll
    for (int r = 0; r < 4; ++r) {
      const int kr = r * 64;
      const float hc = (r == 0) ? hr0 : (r == 1) ? hr1 : (r == 2) ? hr2 : hr3;
#pragma unroll 1
      for (int lb = 0; lb < 64; lb += 16) {
#pragma unroll
        for (int j = 0; j < 8; ++j) wB[j] = Wp[(size_t)(kr + lb + 8 + j) * 64];
#pragma unroll
        for (int j = 0; j < 8; ++j)
          ap[j & 3] = fmaf(wA[j], rlane(hc, lb + j), ap[j & 3]);
        if (kr + lb + 16 < 256) {
#pragma unroll
          for (int j = 0; j < 8; ++j) wA[j] = Wp[(size_t)(kr + lb + 16 + j) * 64];
        }
#pragma unroll
        for (int j = 0; j < 8; ++j)
          ap[j & 3] = fmaf(wB[j], rlane(hc, lb + 8 + j), ap[j & 3]);
      }
    }
    p4[s][hh][d] = (ap[0] + ap[1]) + (ap[2] + ap[3]);
  }
  __syncthreads();
  if (wv < 4) {
    const int s = wv, d = lane;
    const float a4 = p4[s][0][d] + p4[s][1][d] + b4[d];
    float sq = a4 * a4;
#pragma unroll
    for (int off = 32; off; off >>= 1) sq += __shfl_down(sq, off, 64);
    if (lane == 0) out[b0 + s] = 0.5f * sq;
  }
}

// ---------------- divergence v5 (R6, 146us): C/G wave split, 4 waves/SIMD ----------------
// grid (512 sample-quads, 8 row-tiles of 64); block 512 = 8 waves.
// Wave wv: sLoc = wv&3 -> sample g4*4+sLoc; role = (wv<4 ? C : G).
// C-wave: accC[4][4] over rows blockIdx.y*64..+64 x cols 0..64 (64 AGPR).
// Staging: per kc, block stages 16 slots (A2 it0-3 | u1 jt0-3 | A3 it0-3 |
// u4 jt0-3); wave wv stages slots wv*2, wv*2+1 (2 global_load_lds). 3 buffers,
// stage kc+2 at top of kc, end-of-kc s_waitcnt vmcnt(2) (kc+1 done, kc+2 in
// flight -- never 0 in steady state) + raw s_barrier.
// Masks: expand_mask hoisted to LDS (emask); in-loop one broadcast b128 per kc.
// Epilogue: C-waves write accC to LDS (stride-65); G-waves apply m2, reduce.
__device__ __forceinline__ void expand_mask(uint32_t byte8, uint32_t mk[4]) {
#pragma unroll
  for (int i = 0; i < 4; ++i) {
    mk[i] = (((byte8 >> (2 * i)) & 1u) ? 0x0000FFFFu : 0u) |
            (((byte8 >> (2 * i + 1)) & 1u) ? 0xFFFF0000u : 0u);
  }
}

__global__ __launch_bounds__(512, 4) void div_kernel(
    const uint4* __restrict__ A2swz, const uint4* __restrict__ A3swz,
    const uint4* __restrict__ B1swz, const uint4* __restrict__ B4swz,
    const uint32_t* __restrict__ m1p, const uint32_t* __restrict__ m2p,
    const uint32_t* __restrict__ m3p, float* __restrict__ out) {
  __shared__ uint4 sfrag[3][16][64];   // 48KB: [buf][slot][lane]
  __shared__ uint4 emask[8][16][4];    // 8KB: [wave][kc][quad] expanded masks
  const int t = threadIdx.x;
  const int lane = t & 63, wv = t >> 6;
  const int quad = lane >> 4, l15 = lane & 15;
  const int g4 = blockIdx.x;
  const int rowB0 = blockIdx.y * 64;
  const int sLoc = wv & 3;
  const int b = g4 * 4 + sLoc;        // this wave's sample
  const int r16b = blockIdx.y * 4;    // row-16-tile base
  const bool isC = (wv < 4);

  // staging source base for this wave's 2 slots
  const uint4* sb = (wv < 2) ? A2swz : (wv < 4) ? B1swz : (wv < 6) ? A3swz : B4swz;

  f32x4 acc[4][4];
#pragma unroll
  for (int it = 0; it < 4; ++it)
#pragma unroll
    for (int jt = 0; jt < 4; ++jt) acc[it][jt] = (f32x4){0.f, 0.f, 0.f, 0.f};

  // per-wave expanded-mask precompute: lane -> (kc = lane>>2, qd = lane&3).
  // C-waves use m1, G-waves use m3. Wave-private (in-wave lgkmcnt ordering).
  {
    const uint32_t* mp = (isC ? m1p : m3p) + (size_t)b * 16;
    const int kcl = lane >> 2, qd = lane & 3;
    const uint32_t word = mp[kcl];
    uint32_t mk[4];
    expand_mask((word >> (qd * 8)) & 0xFFu, mk);
    uint4 v;
    v.x = mk[0]; v.y = mk[1]; v.z = mk[2]; v.w = mk[3];
    emask[wv][kcl][qd] = v;
  }

  // stage(buf, kc): wave wv stages slots wv*2, wv*2+1
  auto stage = [&](int sbuf, int kc) {
#pragma unroll
    for (int q = 0; q < 2; ++q) {
      const int sub = (wv & 1) * 2 + q;  // it or jt index
      const size_t off = ((wv & 2) == 0)
          ? ((size_t)((r16b + sub) * 16 + kc) * 64 + lane)   // A2 / A3
          : ((size_t)(kc * 4 + sub) * 64 + lane);            // B1 / B4
      lds_load16(sb + off, &sfrag[sbuf][wv * 2 + q][0]);
    }
  };

  stage(0, 0);
  stage(1, 1);
  __builtin_amdgcn_sched_barrier(0);
  asm volatile("s_waitcnt vmcnt(2)" ::: "memory");  // kc=0 staging complete
  __builtin_amdgcn_s_barrier();
  __builtin_amdgcn_sched_barrier(0);

  const int base = isC ? 0 : 8;

#pragma unroll 1
  for (int kc = 0; kc < 16; ++kc) {
    const int rb = kc % 3;
    if (kc < 14) stage((kc + 2) % 3, kc + 2);  // keep 2 kc in flight

    const uint4 mku = emask[wv][kc][quad];  // broadcast ds_read_b128

    uint4 a[4], u[4];
#pragma unroll
    for (int q = 0; q < 4; ++q) {
      a[q] = sfrag[rb][base + q][lane];
      u[q] = sfrag[rb][base + 4 + q][lane];
    }

    short8 bf[4];
#pragma unroll
    for (int jt = 0; jt < 4; ++jt) {
      U16x8 uu;
      uu.u = u[jt];
      uu.u.x &= mku.x; uu.u.y &= mku.y; uu.u.z &= mku.z; uu.u.w &= mku.w;
      bf[jt] = uu.s;
    }
#pragma unroll
    for (int it = 0; it < 4; ++it) {
      U16x8 ua;
      ua.u = a[it];
      const short8 af = ua.s;
#pragma unroll
      for (int jt = 0; jt < 4; ++jt)
        acc[it][jt] = __builtin_amdgcn_mfma_f32_16x16x32_bf16(af, bf[jt], acc[it][jt], 0, 0, 0);
    }

    // counted wait: kc+1's staging (oldest 2) done; kc+2's 2 stay in flight.
    if (kc < 14) {
      asm volatile("s_waitcnt vmcnt(2)" ::: "memory");
    } else if (kc == 14) {
      asm volatile("s_waitcnt vmcnt(0)" ::: "memory");  // drain last stage
    }
    if (kc < 15) {
      __builtin_amdgcn_s_barrier();
      __builtin_amdgcn_sched_barrier(0);  // no ds_read hoisting above barrier
    }
  }

  // ---- epilogue: exchange C via LDS (2 halves of 32 rows), G applies m2 ----
  // C/D layout: row = it*16 + quad*4 + reg, col = jt*16 + l15.
  __syncthreads();  // all sfrag reads done; safe to overlay
  float* cxf = (float*)&sfrag[0][0][0];  // [sample][32 rows][stride 65]
  float dsum = 0.f;
  const uint32_t* m2w = m2p + (size_t)b * 16;
#pragma unroll
  for (int h = 0; h < 2; ++h) {
    if (isC) {
#pragma unroll
      for (int ith = 0; ith < 2; ++ith)
#pragma unroll
        for (int jt = 0; jt < 4; ++jt) {
          float* crow = &cxf[((size_t)sLoc * 32 + ith * 16 + quad * 4) * 65 +
                             jt * 16 + l15];
          crow[0 * 65] = acc[h * 2 + ith][jt][0];
          crow[1 * 65] = acc[h * 2 + ith][jt][1];
          crow[2 * 65] = acc[h * 2 + ith][jt][2];
          crow[3 * 65] = acc[h * 2 + ith][jt][3];
        }
    }
    __syncthreads();
    if (!isC) {
#pragma unroll
      for (int ith = 0; ith < 2; ++ith) {
        const int it = h * 2 + ith;
        const int rloc = it * 16 + quad * 4;
        const uint32_t md = m2w[(rowB0 + rloc) >> 5];
        const uint32_t bits = (md >> (rloc & 31)) & 0xFu;
        const float w0 = (bits & 1u) ? 1.f : 0.f;
        const float w1 = (bits & 2u) ? 1.f : 0.f;
        const float w2 = (bits & 4u) ? 1.f : 0.f;
        const float w3 = (bits & 8u) ? 1.f : 0.f;
#pragma unroll
        for (int jt = 0; jt < 4; ++jt) {
          const float* crow = &cxf[((size_t)sLoc * 32 + ith * 16 + quad * 4) * 65 +
                                   jt * 16 + l15];
          dsum = fmaf(w0, acc[it][jt][0] * crow[0 * 65], dsum);
          dsum = fmaf(w1, acc[it][jt][1] * crow[1 * 65], dsum);
          dsum = fmaf(w2, acc[it][jt][2] * crow[2 * 65], dsum);
          dsum = fmaf(w3, acc[it][jt][3] * crow[3 * 65], dsum);
        }
      }
    }
    __syncthreads();
  }
  if (!isC) {
#pragma unroll
    for (int off = 32; off; off >>= 1) dsum += __shfl_down(dsum, off, 64);
    if (lane == 0) atomicAdd(out + b, dsum);
  }
}

extern "C" void kernel_launch(void* const* d_in, const int* in_sizes, int n_in,
                              void* d_out, int out_size, void* d_ws, size_t ws_size,
                              hipStream_t stream) {
  const float* x  = (const float*)d_in[0];
  const float* W1 = (const float*)d_in[1];
  const float* b1 = (const float*)d_in[2];
  const float* W2 = (const float*)d_in[3];
  const float* b2 = (const float*)d_in[4];
  const float* W3 = (const float*)d_in[5];
  const float* b3 = (const float*)d_in[6];
  const float* W4 = (const float*)d_in[7];
  const float* b4 = (const float*)d_in[8];
  float* out = (float*)d_out;

  // workspace layout (bytes), total 3,932,160:
  char* ws = (char*)d_ws;
  uint16_t* A2swz = (uint16_t*)(ws + 0);        // 524288
  uint16_t* A3swz = (uint16_t*)(ws + 524288);   // 524288
  uint16_t* B1swz = (uint16_t*)(ws + 1048576);  // 65536
  uint16_t* B4swz = (uint16_t*)(ws + 1114112);  // 65536
  float*    W2Tf  = (float*)(ws + 1179648);     // 1048576
  float*    W3Tf  = (float*)(ws + 2228224);     // 1048576
  float*    W1Tf  = (float*)(ws + 3276800);     // 131072
  float*    W4Tf  = (float*)(ws + 3407872);     // 131072
  uint32_t* m1p   = (uint32_t*)(ws + 3538944);  // 131072 (2048 x 512 bits)
  uint32_t* m2p   = (uint32_t*)(ws + 3670016);  // 131072
  uint32_t* m3p   = (uint32_t*)(ws + 3801088);  // 131072
  if (ws_size < 3932160) return;

  convert_kernel<<<4608, 256, 0, stream>>>(W1, W2, W3, W4,
                                           A2swz, A3swz, B1swz, B4swz,
                                           W2Tf, W3Tf, W1Tf, W4Tf);
  forward_kernel<<<512, 512, 0, stream>>>(x, W1Tf, b1, W2Tf, b2, W3Tf, b3,
                                          W4Tf, b4, m1p, m2p, m3p, out);
  div_kernel<<<dim3(512, 8), 512, 0, stream>>>((const uint4*)A2swz,
                                               (const uint4*)A3swz,
                                               (const uint4*)B1swz,
                                               (const uint4*)B4swz,
                                               m1p, m2p, m3p, out);
}

// Round 9
// 273.354 us; speedup vs baseline: 1.1337x; 1.1337x over previous
//
#include <hip/hip_runtime.h>
#include <stdint.h>

// ScoreMatching: B=2048, D=64, H=512.
// out[b] = 0.5*||s_b||^2 + tr(W4 M3 W3 M2 W2 M1 W1)_b
// div_b = sum_{i,d} m2[i] * C[i,d] * G[i,d]
//   C = W2 @ (M1 .* W1)      [512 x 64]   A-frag = W2 rows,  B-frag = W1T rows
//   G = W3^T @ (M3 .* W4^T)  [512 x 64]   A-frag = W3T rows, B-frag = W4 rows
// R13 changes:
//  - forward: REVERT to v5 (R5; readlane v6 regressed 110->154us: runtime-index
//    v_readlane costs VALU issue + SGPR hazards per FMA).
//  - div v7: LDS-volume cut. The k-mask commutes to the A operand
//    (C[i,d] = sum_k W2[i,k] m1[k] W1T[k,d]), so waves repartition as
//    (role C/G x it-quarter q) over ALL 4 samples: per kc read 1 A-frag +
//    4 shared B-frags (5KB vs 9KB per wave-kc; per-CU 144->80KB/slot ->
//    MFMA becomes the binding pipe). 16 MFMA/wave-kc unchanged
//    (acc[sample][jt], 64 AGPR). emask now cross-wave [role][sample] ->
//    lgkmcnt(0) before first barrier. Staging/grid/occupancy unchanged.

typedef __attribute__((ext_vector_type(8))) short short8;
typedef __attribute__((ext_vector_type(4))) float f32x4;

union U16x8 {
  uint4 u;
  short8 s;
};

__device__ __forceinline__ uint16_t f2bf(float f) {
  uint32_t u = __float_as_uint(f);
  uint32_t lsb = (u >> 16) & 1u;
  u += 0x7FFFu + lsb;  // round-to-nearest-even
  return (uint16_t)(u >> 16);
}

// async global->LDS, 16B per lane: lane's data lands at lds_base + lane*16.
__device__ __forceinline__ void lds_load16(const uint4* gsrc, uint4* ldst) {
  __builtin_amdgcn_global_load_lds(
      (const __attribute__((address_space(1))) void*)gsrc,
      (__attribute__((address_space(3))) void*)ldst, 16, 0, 0);
}

// ---------------- convert: build swizzled bf16 fragments + fp32 transposes ----------------
// Fragment order (16x16x32 bf16 MFMA): lane = quad*16 + l15 holds 8 contiguous
// bf16 = 16 B; A-frag element (m=l15, k=quad*8+j); B-frag (n=l15, k=quad*8+j).
// A2swz[((r16*16 + kc)*64 + lane)*8 + j] = W2 [r16*16+l15][kc*32+quad*8+j]
// A3swz[  same index                   ] = W3T[r16*16+l15][kc*32+quad*8+j]
// B1swz[((kc*4 + jt)*64 + lane)*8 + j]  = W1T[jt*16+l15 ][kc*32+quad*8+j]
// B4swz[  same index                 ]  = W4 [jt*16+l15 ][kc*32+quad*8+j]
__global__ __launch_bounds__(256) void convert_kernel(
    const float* __restrict__ W1, const float* __restrict__ W2,
    const float* __restrict__ W3, const float* __restrict__ W4,
    uint16_t* __restrict__ A2swz, uint16_t* __restrict__ A3swz,
    uint16_t* __restrict__ B1swz, uint16_t* __restrict__ B4swz,
    float* __restrict__ W2Tf, float* __restrict__ W3Tf,
    float* __restrict__ W1Tf, float* __restrict__ W4Tf) {
  const int i = blockIdx.x * 256 + threadIdx.x;
  if (i < 262144) {  // A2swz
    const int e = i;
    const int f = e >> 3, j = e & 7;
    const int lane = f & 63, fk = f >> 6;
    const int kc = fk & 15, r16 = fk >> 4;
    const int l15 = lane & 15, quad = lane >> 4;
    const int row = r16 * 16 + l15, col = kc * 32 + quad * 8 + j;
    A2swz[e] = f2bf(W2[row * 512 + col]);
  } else if (i < 524288) {  // A3swz (= W3 transposed)
    const int e = i - 262144;
    const int f = e >> 3, j = e & 7;
    const int lane = f & 63, fk = f >> 6;
    const int kc = fk & 15, r16 = fk >> 4;
    const int l15 = lane & 15, quad = lane >> 4;
    const int row = r16 * 16 + l15, col = kc * 32 + quad * 8 + j;
    A3swz[e] = f2bf(W3[col * 512 + row]);
  } else if (i < 557056) {  // B1swz (= W1 transposed)
    const int e = i - 524288;
    const int f = e >> 3, j = e & 7;
    const int lane = f & 63, fk = f >> 6;
    const int kc = fk >> 2, jt = fk & 3;
    const int l15 = lane & 15, quad = lane >> 4;
    const int d = jt * 16 + l15, col = kc * 32 + quad * 8 + j;
    B1swz[e] = f2bf(W1[col * 64 + d]);
  } else if (i < 589824) {  // B4swz (= W4 row-major)
    const int e = i - 557056;
    const int f = e >> 3, j = e & 7;
    const int lane = f & 63, fk = f >> 6;
    const int kc = fk >> 2, jt = fk & 3;
    const int l15 = lane & 15, quad = lane >> 4;
    const int d = jt * 16 + l15, col = kc * 32 + quad * 8 + j;
    B4swz[e] = f2bf(W4[d * 512 + col]);
  } else if (i < 851968) {  // W2Tf [k][j]
    const int e = i - 589824;
    const int k = e >> 9, jj = e & 511;
    W2Tf[e] = W2[jj * 512 + k];
  } else if (i < 1114112) {  // W3Tf [k][j]
    const int e = i - 851968;
    const int k = e >> 9, jj = e & 511;
    W3Tf[e] = W3[jj * 512 + k];
  } else if (i < 1146880) {  // W1Tf [k][j], k<64
    const int e = i - 1114112;
    const int k = e >> 9, jj = e & 511;
    W1Tf[e] = W1[jj * 64 + k];
  } else if (i < 1179648) {  // W4Tf [k][d]
    const int e = i - 1146880;
    const int k = e >> 6, d = e & 63;
    W4Tf[e] = W4[d * 512 + k];
  }
}

// ---------------- forward v5 (fp32): W register double-buffer ----------------
// 512 blocks x 512 threads (8 waves); 4 samples/block -> 2 blocks/CU,
// 4 waves/SIMD. Thread t owns unit j=t for 4 samples.
// Hidden-layer inner loop: named wA[8]/wB[8] register double buffer; the 8
// loads for the NEXT half-step are issued before computing the current one.
// Mask: wave w covers units w*64..w*64+63 -> __ballot(a>0) = words 2w, 2w+1.
__device__ __forceinline__ void relu_store_mask4(
    float acc[4], float (*hdst)[4], uint32_t* __restrict__ mbase,
    int t, int lane, int wv) {
#pragma unroll
  for (int s = 0; s < 4; ++s) {
    const unsigned long long bal = __ballot(acc[s] > 0.f);
    if (lane == 0) {
      uint2 w2;
      w2.x = (uint32_t)bal;
      w2.y = (uint32_t)(bal >> 32);
      *(uint2*)(mbase + (size_t)s * 16 + 2 * wv) = w2;
    }
  }
  float4 r;
  r.x = acc[0] > 0.f ? acc[0] : 0.f;
  r.y = acc[1] > 0.f ? acc[1] : 0.f;
  r.z = acc[2] > 0.f ? acc[2] : 0.f;
  r.w = acc[3] > 0.f ? acc[3] : 0.f;
  *(float4*)&hdst[t][0] = r;
}

__device__ __forceinline__ void fwd_layer(
    const float* __restrict__ WT, const float* __restrict__ bias,
    const float (* __restrict__ src)[4], float (* __restrict__ dst)[4],
    uint32_t* __restrict__ mbase, int t, int lane, int wv, int K) {
  float acc[4];
  {
    const float bj = bias[t];
    acc[0] = bj; acc[1] = bj; acc[2] = bj; acc[3] = bj;
  }
  const float* Wp = WT + t;
  float wA[8], wB[8];
#pragma unroll
  for (int j = 0; j < 8; ++j) wA[j] = Wp[(size_t)j * 512];
#pragma unroll 1
  for (int kb = 0; kb < K; kb += 16) {
#pragma unroll
    for (int j = 0; j < 8; ++j) wB[j] = Wp[(size_t)(kb + 8 + j) * 512];
#pragma unroll
    for (int j = 0; j < 8; ++j) {
      const float4 h = *(const float4*)&src[kb + j][0];
      const float w = wA[j];
      acc[0] = fmaf(w, h.x, acc[0]); acc[1] = fmaf(w, h.y, acc[1]);
      acc[2] = fmaf(w, h.z, acc[2]); acc[3] = fmaf(w, h.w, acc[3]);
    }
    if (kb + 16 < K) {
#pragma unroll
      for (int j = 0; j < 8; ++j) wA[j] = Wp[(size_t)(kb + 16 + j) * 512];
    }
#pragma unroll
    for (int j = 0; j < 8; ++j) {
      const float4 h = *(const float4*)&src[kb + 8 + j][0];
      const float w = wB[j];
      acc[0] = fmaf(w, h.x, acc[0]); acc[1] = fmaf(w, h.y, acc[1]);
      acc[2] = fmaf(w, h.z, acc[2]); acc[3] = fmaf(w, h.w, acc[3]);
    }
  }
  relu_store_mask4(acc, dst, mbase, t, lane, wv);
}

__global__ __launch_bounds__(512) void forward_kernel(
    const float* __restrict__ x,
    const float* __restrict__ W1Tf, const float* __restrict__ b1,
    const float* __restrict__ W2Tf, const float* __restrict__ b2,
    const float* __restrict__ W3Tf, const float* __restrict__ b3,
    const float* __restrict__ W4Tf, const float* __restrict__ b4,
    uint32_t* __restrict__ m1p, uint32_t* __restrict__ m2p,
    uint32_t* __restrict__ m3p, float* __restrict__ out) {
  __shared__ float xs[64][4];   // [k][sample]
  __shared__ float hA[512][4];  // [unit][sample]
  __shared__ float hB[512][4];
  __shared__ float p4[4][2][64];  // layer-4 partials [sample][k-half][d]
  const int t = threadIdx.x;
  const int lane = t & 63, wv = t >> 6;
  const int b0 = blockIdx.x * 4;

  if (t < 256) {
    const int k = t >> 2, s = t & 3;  // 256 threads cover 4 samples x 64 k
    xs[k][s] = x[(size_t)(b0 + s) * 64 + k];
  }
  __syncthreads();

  fwd_layer(W1Tf, b1, xs, hA, m1p + (size_t)b0 * 16, t, lane, wv, 64);
  __syncthreads();
  fwd_layer(W2Tf, b2, hA, hB, m2p + (size_t)b0 * 16, t, lane, wv, 512);
  __syncthreads();
  fwd_layer(W3Tf, b3, hB, hA, m3p + (size_t)b0 * 16, t, lane, wv, 512);
  __syncthreads();

  // ---- layer 4 (K=512, D=64) + 0.5*||s||^2 : 8 waves, k-halves ----
  {
    const int s = wv & 3, hh = wv >> 2, d = lane;
    const int k0 = hh * 256;
    const float* Wp = W4Tf + (size_t)k0 * 64 + d;
    float ap[4] = {0.f, 0.f, 0.f, 0.f};
    float wA[8], wB[8];
#pragma unroll
    for (int j = 0; j < 8; ++j) wA[j] = Wp[(size_t)j * 64];
#pragma unroll 1
    for (int kb = 0; kb < 256; kb += 16) {
#pragma unroll
      for (int j = 0; j < 8; ++j) wB[j] = Wp[(size_t)(kb + 8 + j) * 64];
#pragma unroll
      for (int j = 0; j < 8; ++j)
        ap[j & 3] = fmaf(wA[j], hA[k0 + kb + j][s], ap[j & 3]);
      if (kb + 16 < 256) {
#pragma unroll
        for (int j = 0; j < 8; ++j) wA[j] = Wp[(size_t)(kb + 16 + j) * 64];
      }
#pragma unroll
      for (int j = 0; j < 8; ++j)
        ap[j & 3] = fmaf(wB[j], hA[k0 + kb + 8 + j][s], ap[j & 3]);
    }
    p4[s][hh][d] = (ap[0] + ap[1]) + (ap[2] + ap[3]);
  }
  __syncthreads();
  if (wv < 4) {
    const int s = wv, d = lane;
    const float a4 = p4[s][0][d] + p4[s][1][d] + b4[d];
    float sq = a4 * a4;
#pragma unroll
    for (int off = 32; off; off >>= 1) sq += __shfl_down(sq, off, 64);
    if (lane == 0) out[b0 + s] = 0.5f * sq;
  }
}

// ---------------- divergence v7: mask-on-A, (role x it-quarter) waves ----------------
// grid (512 sample-quads, 8 row-tiles of 64); block 512 = 8 waves.
// Wave wv: role = (wv<4 ? C : G), q = wv&3 (it-quarter: rows q*16..q*16+16).
// Wave computes its 16-row strip for ALL 4 samples: per kc read 1 A-frag +
// 4 shared B-frags; per sample AND the k-mask into the A-frag (m1 for C, m3
// for G -- the mask commutes onto A since it indexes k); 16 MFMA into
// acc[sample][jt] (64 AGPR).
// Staging identical to v5: 16 slots (A2 it0-3 | u1 jt0-3 | A3 it0-3 |
// u4 jt0-3), wave wv stages slots wv*2, wv*2+1; 3 buffers, stage kc+2 during
// kc, end-of-kc vmcnt(2) + raw s_barrier (never 0 in steady state).
// emask2[role][sample] precomputed to LDS (cross-wave -> lgkmcnt(0) before
// the first barrier). Epilogue: C-waves write strips to LDS (stride 65),
// G-waves apply m2 and reduce; 4 atomicAdds per G-wave.
__device__ __forceinline__ void expand_mask(uint32_t byte8, uint32_t mk[4]) {
#pragma unroll
  for (int i = 0; i < 4; ++i) {
    mk[i] = (((byte8 >> (2 * i)) & 1u) ? 0x0000FFFFu : 0u) |
            (((byte8 >> (2 * i + 1)) & 1u) ? 0xFFFF0000u : 0u);
  }
}

__global__ __launch_bounds__(512, 4) void div_kernel(
    const uint4* __restrict__ A2swz, const uint4* __restrict__ A3swz,
    const uint4* __restrict__ B1swz, const uint4* __restrict__ B4swz,
    const uint32_t* __restrict__ m1p, const uint32_t* __restrict__ m2p,
    const uint32_t* __restrict__ m3p, float* __restrict__ out) {
  __shared__ uint4 sfrag[3][16][64];      // 48KB: [buf][slot][lane]
  __shared__ uint4 emask2[2][4][16][4];   // 8KB: [role][sample][kc][quad]
  const int t = threadIdx.x;
  const int lane = t & 63, wv = t >> 6;
  const int quad = lane >> 4, l15 = lane & 15;
  const int g4 = blockIdx.x;
  const int rowB0 = blockIdx.y * 64;
  const int q = wv & 3;               // it-quarter (16-row strip)
  const int r16b = blockIdx.y * 4;    // row-16-tile base
  const bool isC = (wv < 4);
  const int role = isC ? 0 : 1;

  // staging source base for this wave's 2 slots (identical to v5)
  const uint4* sb = (wv < 2) ? A2swz : (wv < 4) ? B1swz : (wv < 6) ? A3swz : B4swz;

  f32x4 acc[4][4];  // [sample][jt]
#pragma unroll
  for (int s = 0; s < 4; ++s)
#pragma unroll
    for (int jt = 0; jt < 4; ++jt) acc[s][jt] = (f32x4){0.f, 0.f, 0.f, 0.f};

  // expanded-mask precompute: wave wv -> (role r = wv>>2, sample s = wv&3).
  // lane -> (kc = lane>>2, qd = lane&3). Cross-wave consumers!
  {
    const int r = wv >> 2, s = wv & 3;
    const uint32_t* mp = (r == 0 ? m1p : m3p) + (size_t)(g4 * 4 + s) * 16;
    const int kcl = lane >> 2, qd = lane & 3;
    const uint32_t word = mp[kcl];
    uint32_t mk[4];
    expand_mask((word >> (qd * 8)) & 0xFFu, mk);
    uint4 v;
    v.x = mk[0]; v.y = mk[1]; v.z = mk[2]; v.w = mk[3];
    emask2[r][s][kcl][qd] = v;
  }

  // stage(buf, kc): wave wv stages slots wv*2, wv*2+1 (identical to v5)
  auto stage = [&](int sbuf, int kc) {
#pragma unroll
    for (int qq = 0; qq < 2; ++qq) {
      const int sub = (wv & 1) * 2 + qq;  // it or jt index
      const size_t off = ((wv & 2) == 0)
          ? ((size_t)((r16b + sub) * 16 + kc) * 64 + lane)   // A2 / A3
          : ((size_t)(kc * 4 + sub) * 64 + lane);            // B1 / B4
      lds_load16(sb + off, &sfrag[sbuf][wv * 2 + qq][0]);
    }
  };

  stage(0, 0);
  stage(1, 1);
  __builtin_amdgcn_sched_barrier(0);
  // drain emask2 ds_writes (cross-wave) AND kc=0 staging before the barrier
  asm volatile("s_waitcnt vmcnt(2) lgkmcnt(0)" ::: "memory");
  __builtin_amdgcn_s_barrier();
  __builtin_amdgcn_sched_barrier(0);

  const int abase = isC ? 0 : 8;   // A2 / A3 slots
  const int ubase = isC ? 4 : 12;  // u1 / u4 slots

#pragma unroll 1
  for (int kc = 0; kc < 16; ++kc) {
    const int rb = kc % 3;
    if (kc < 14) stage((kc + 2) % 3, kc + 2);  // keep 2 kc in flight

    const uint4 a1 = sfrag[rb][abase + q][lane];  // this wave's A-frag
    uint4 u[4];
#pragma unroll
    for (int jt = 0; jt < 4; ++jt) u[jt] = sfrag[rb][ubase + jt][lane];

    short8 bu[4];
#pragma unroll
    for (int jt = 0; jt < 4; ++jt) {
      U16x8 uu;
      uu.u = u[jt];
      bu[jt] = uu.s;
    }

#pragma unroll
    for (int s = 0; s < 4; ++s) {
      const uint4 mku = emask2[role][s][kc][quad];  // 16-lane-group broadcast
      U16x8 am;
      am.u.x = a1.x & mku.x;
      am.u.y = a1.y & mku.y;
      am.u.z = a1.z & mku.z;
      am.u.w = a1.w & mku.w;
      const short8 af = am.s;
#pragma unroll
      for (int jt = 0; jt < 4; ++jt)
        acc[s][jt] = __builtin_amdgcn_mfma_f32_16x16x32_bf16(af, bu[jt], acc[s][jt], 0, 0, 0);
    }

    // counted wait: kc+1's staging (oldest 2) done; kc+2's 2 stay in flight.
    if (kc < 14) {
      asm volatile("s_waitcnt vmcnt(2)" ::: "memory");
    } else if (kc == 14) {
      asm volatile("s_waitcnt vmcnt(0)" ::: "memory");  // drain last stage
    }
    if (kc < 15) {
      __builtin_amdgcn_s_barrier();
      __builtin_amdgcn_sched_barrier(0);  // no ds_read hoisting above barrier
    }
  }

  // ---- epilogue: C-waves write strips to LDS, G-waves apply m2, reduce ----
  // C/D layout within 16x16 tile: row = quad*4 + reg, col = jt*16 + l15.
  // cxf group g = q*2 + (s&1): [8 groups][16 rows][stride 65] = 33.3KB.
  __syncthreads();  // all sfrag reads done; safe to overlay
  float* cxf = (float*)&sfrag[0][0][0];
  float dsum[4] = {0.f, 0.f, 0.f, 0.f};
#pragma unroll
  for (int h = 0; h < 2; ++h) {
    if (isC) {
#pragma unroll
      for (int sh = 0; sh < 2; ++sh) {
        const int s = h * 2 + sh;
#pragma unroll
        for (int jt = 0; jt < 4; ++jt) {
          float* crow = &cxf[((size_t)(q * 2 + sh) * 16 + quad * 4) * 65 +
                             jt * 16 + l15];
          crow[0 * 65] = acc[s][jt][0];
          crow[1 * 65] = acc[s][jt][1];
          crow[2 * 65] = acc[s][jt][2];
          crow[3 * 65] = acc[s][jt][3];
        }
      }
    }
    __syncthreads();
    if (!isC) {
#pragma unroll
      for (int sh = 0; sh < 2; ++sh) {
        const int s = h * 2 + sh;
        const uint32_t* m2w = m2p + (size_t)(g4 * 4 + s) * 16;
        const int rloc = q * 16 + quad * 4;
        const uint32_t md = m2w[(rowB0 + rloc) >> 5];
        const uint32_t bits = (md >> (rloc & 31)) & 0xFu;
        const float w0 = (bits & 1u) ? 1.f : 0.f;
        const float w1 = (bits & 2u) ? 1.f : 0.f;
        const float w2 = (bits & 4u) ? 1.f : 0.f;
        const float w3 = (bits & 8u) ? 1.f : 0.f;
#pragma unroll
        for (int jt = 0; jt < 4; ++jt) {
          const float* crow = &cxf[((size_t)(q * 2 + sh) * 16 + quad * 4) * 65 +
                                   jt * 16 + l15];
          dsum[s] = fmaf(w0, acc[s][jt][0] * crow[0 * 65], dsum[s]);
          dsum[s] = fmaf(w1, acc[s][jt][1] * crow[1 * 65], dsum[s]);
          dsum[s] = fmaf(w2, acc[s][jt][2] * crow[2 * 65], dsum[s]);
          dsum[s] = fmaf(w3, acc[s][jt][3] * crow[3 * 65], dsum[s]);
        }
      }
    }
    __syncthreads();
  }
  if (!isC) {
#pragma unroll
    for (int s = 0; s < 4; ++s) {
      float v = dsum[s];
#pragma unroll
      for (int off = 32; off; off >>= 1) v += __shfl_down(v, off, 64);
      if (lane == 0) atomicAdd(out + (g4 * 4 + s), v);
    }
  }
}

extern "C" void kernel_launch(void* const* d_in, const int* in_sizes, int n_in,
                              void* d_out, int out_size, void* d_ws, size_t ws_size,
                              hipStream_t stream) {
  const float* x  = (const float*)d_in[0];
  const float* W1 = (const float*)d_in[1];
  const float* b1 = (const float*)d_in[2];
  const float* W2 = (const float*)d_in[3];
  const float* b2 = (const float*)d_in[4];
  const float* W3 = (const float*)d_in[5];
  const float* b3 = (const float*)d_in[6];
  const float* W4 = (const float*)d_in[7];
  const float* b4 = (const float*)d_in[8];
  float* out = (float*)d_out;

  // workspace layout (bytes), total 3,932,160:
  char* ws = (char*)d_ws;
  uint16_t* A2swz = (uint16_t*)(ws + 0);        // 524288
  uint16_t* A3swz = (uint16_t*)(ws + 524288);   // 524288
  uint16_t* B1swz = (uint16_t*)(ws + 1048576);  // 65536
  uint16_t* B4swz = (uint16_t*)(ws + 1114112);  // 65536
  float*    W2Tf  = (float*)(ws + 1179648);     // 1048576
  float*    W3Tf  = (float*)(ws + 2228224);     // 1048576
  float*    W1Tf  = (float*)(ws + 3276800);     // 131072
  float*    W4Tf  = (float*)(ws + 3407872);     // 131072
  uint32_t* m1p   = (uint32_t*)(ws + 3538944);  // 131072 (2048 x 512 bits)
  uint32_t* m2p   = (uint32_t*)(ws + 3670016);  // 131072
  uint32_t* m3p   = (uint32_t*)(ws + 3801088);  // 131072
  if (ws_size < 3932160) return;

  convert_kernel<<<4608, 256, 0, stream>>>(W1, W2, W3, W4,
                                           A2swz, A3swz, B1swz, B4swz,
                                           W2Tf, W3Tf, W1Tf, W4Tf);
  forward_kernel<<<512, 512, 0, stream>>>(x, W1Tf, b1, W2Tf, b2, W3Tf, b3,
                                          W4Tf, b4, m1p, m2p, m3p, out);
  div_kernel<<<dim3(512, 8), 512, 0, stream>>>((const uint4*)A2swz,
                                               (const uint4*)A3swz,
                                               (const uint4*)B1swz,
                                               (const uint4*)B4swz,
                                               m1p, m2p, m3p, out);
}

// Round 10
// 264.372 us; speedup vs baseline: 1.1723x; 1.0340x over previous
//
#include <hip/hip_runtime.h>
#include <stdint.h>

// ScoreMatching: B=2048, D=64, H=512.
// out[b] = 0.5*||s_b||^2 + tr(W4 M3 W3 M2 W2 M1 W1)_b
// div_b = sum_{i,d} m2[i] * C[i,d] * G[i,d]
//   C = W2 @ (M1 .* W1)      [512 x 64]   A-frag = W2 rows,  B-frag = W1T rows
//   G = W3^T @ (M3 .* W4^T)  [512 x 64]   A-frag = W3T rows, B-frag = W4 rows
// R14 changes:
//  - div: REVERT to v5 (R6/R8, 146us x3). v7 mask-on-A didn't cut LDS reads
//    (emask became per-sample: 5+4 = 9 reads/wave-kc, same as 9) and 4x'd the
//    atomicAdds. v5 restored verbatim.
//  - forward v8: invariant ~110us = broadcast ds_read_b128 cost (12cyc each,
//    16 waves x 1024/CU = 82us model). Lever = FMAs per broadcast read, which
//    needs fewer/fatter waves -> split K across waves to keep 512 blocks:
//    block = 4 samples, 4 waves; wave kh owns k-quarter; thread = 8 units x
//    4 samples -> per k: 1 broadcast b128 + 8 coalesced w + 32 FMA (4x v5's
//    FMA/read). Deterministic pairwise combine of 4 partials via LDS (fixed
//    order -> mask-stable); ballot mask layout unchanged. Layer 4 kh-split too.
//    LDS model 197K -> 37K cyc/CU; new floor = 1GB W L2 traffic (~30us).

typedef __attribute__((ext_vector_type(8))) short short8;
typedef __attribute__((ext_vector_type(4))) float f32x4;

union U16x8 {
  uint4 u;
  short8 s;
};

__device__ __forceinline__ uint16_t f2bf(float f) {
  uint32_t u = __float_as_uint(f);
  uint32_t lsb = (u >> 16) & 1u;
  u += 0x7FFFu + lsb;  // round-to-nearest-even
  return (uint16_t)(u >> 16);
}

// async global->LDS, 16B per lane: lane's data lands at lds_base + lane*16.
__device__ __forceinline__ void lds_load16(const uint4* gsrc, uint4* ldst) {
  __builtin_amdgcn_global_load_lds(
      (const __attribute__((address_space(1))) void*)gsrc,
      (__attribute__((address_space(3))) void*)ldst, 16, 0, 0);
}

// ---------------- convert: build swizzled bf16 fragments + fp32 transposes ----------------
// Fragment order (16x16x32 bf16 MFMA): lane = quad*16 + l15 holds 8 contiguous
// bf16 = 16 B; A-frag element (m=l15, k=quad*8+j); B-frag (n=l15, k=quad*8+j).
// A2swz[((r16*16 + kc)*64 + lane)*8 + j] = W2 [r16*16+l15][kc*32+quad*8+j]
// A3swz[  same index                   ] = W3T[r16*16+l15][kc*32+quad*8+j]
// B1swz[((kc*4 + jt)*64 + lane)*8 + j]  = W1T[jt*16+l15 ][kc*32+quad*8+j]
// B4swz[  same index                 ]  = W4 [jt*16+l15 ][kc*32+quad*8+j]
__global__ __launch_bounds__(256) void convert_kernel(
    const float* __restrict__ W1, const float* __restrict__ W2,
    const float* __restrict__ W3, const float* __restrict__ W4,
    uint16_t* __restrict__ A2swz, uint16_t* __restrict__ A3swz,
    uint16_t* __restrict__ B1swz, uint16_t* __restrict__ B4swz,
    float* __restrict__ W2Tf, float* __restrict__ W3Tf,
    float* __restrict__ W1Tf, float* __restrict__ W4Tf) {
  const int i = blockIdx.x * 256 + threadIdx.x;
  if (i < 262144) {  // A2swz
    const int e = i;
    const int f = e >> 3, j = e & 7;
    const int lane = f & 63, fk = f >> 6;
    const int kc = fk & 15, r16 = fk >> 4;
    const int l15 = lane & 15, quad = lane >> 4;
    const int row = r16 * 16 + l15, col = kc * 32 + quad * 8 + j;
    A2swz[e] = f2bf(W2[row * 512 + col]);
  } else if (i < 524288) {  // A3swz (= W3 transposed)
    const int e = i - 262144;
    const int f = e >> 3, j = e & 7;
    const int lane = f & 63, fk = f >> 6;
    const int kc = fk & 15, r16 = fk >> 4;
    const int l15 = lane & 15, quad = lane >> 4;
    const int row = r16 * 16 + l15, col = kc * 32 + quad * 8 + j;
    A3swz[e] = f2bf(W3[col * 512 + row]);
  } else if (i < 557056) {  // B1swz (= W1 transposed)
    const int e = i - 524288;
    const int f = e >> 3, j = e & 7;
    const int lane = f & 63, fk = f >> 6;
    const int kc = fk >> 2, jt = fk & 3;
    const int l15 = lane & 15, quad = lane >> 4;
    const int d = jt * 16 + l15, col = kc * 32 + quad * 8 + j;
    B1swz[e] = f2bf(W1[col * 64 + d]);
  } else if (i < 589824) {  // B4swz (= W4 row-major)
    const int e = i - 557056;
    const int f = e >> 3, j = e & 7;
    const int lane = f & 63, fk = f >> 6;
    const int kc = fk >> 2, jt = fk & 3;
    const int l15 = lane & 15, quad = lane >> 4;
    const int d = jt * 16 + l15, col = kc * 32 + quad * 8 + j;
    B4swz[e] = f2bf(W4[d * 512 + col]);
  } else if (i < 851968) {  // W2Tf [k][j]
    const int e = i - 589824;
    const int k = e >> 9, jj = e & 511;
    W2Tf[e] = W2[jj * 512 + k];
  } else if (i < 1114112) {  // W3Tf [k][j]
    const int e = i - 851968;
    const int k = e >> 9, jj = e & 511;
    W3Tf[e] = W3[jj * 512 + k];
  } else if (i < 1146880) {  // W1Tf [k][j], k<64
    const int e = i - 1114112;
    const int k = e >> 9, jj = e & 511;
    W1Tf[e] = W1[jj * 64 + k];
  } else if (i < 1179648) {  // W4Tf [k][d]
    const int e = i - 1146880;
    const int k = e >> 6, d = e & 63;
    W4Tf[e] = W4[d * 512 + k];
  }
}

// ---------------- forward v8 (fp32): K-split waves, 8 units x 4 samples ----------------
// 512 blocks x 256 threads (4 waves); block = 4 samples, 2 blocks/CU.
// Wave kh = t>>6 owns k-quarter [kh*KPW, kh*KPW+KPW); thread owns units
// {lane, lane+64, ..., lane+448}. Per k: 1 broadcast b128 (h[k][0..3]) +
// 8 coalesced w-loads + 32 FMA. Partials -> pa[kh] in LDS; combine pass
// (2 passes x 256 thr) does deterministic ((p0+p1)+(p2+p3))+bias, ReLU,
// ballot masks (wave wv covers units pass*256+wv*64.. -> words pass*8+2wv),
// writes h_next. W/h prefetch one k ahead; final prefetch over-reads into
// adjacent workspace/LDS arrays (values unused; pa declared last).
__device__ __forceinline__ float4 frelu4(float a0, float a1, float a2, float a3) {
  float4 r;
  r.x = a0 > 0.f ? a0 : 0.f;
  r.y = a1 > 0.f ? a1 : 0.f;
  r.z = a2 > 0.f ? a2 : 0.f;
  r.w = a3 > 0.f ? a3 : 0.f;
  return r;
}

template <int KPW>
__device__ __forceinline__ void fwd_layer8(
    const float* __restrict__ WT, const float* __restrict__ bias,
    const float4* __restrict__ src, float4* __restrict__ dst,
    float4 (* __restrict__ pa)[512], uint32_t* __restrict__ mbase,
    int t, int lane, int kh) {
  float acc[8][4];
#pragma unroll
  for (int p = 0; p < 8; ++p)
#pragma unroll
    for (int s = 0; s < 4; ++s) acc[p][s] = 0.f;

  const int k0 = kh * KPW;
  const float* Wb = WT + (size_t)k0 * 512 + lane;
  float wA[8], wB[8];
#pragma unroll
  for (int p = 0; p < 8; ++p) wA[p] = Wb[p * 64];
  float4 hA_ = src[k0];

#pragma unroll 1
  for (int kk = 0; kk < KPW; kk += 2) {
    const float4 hB_ = src[k0 + kk + 1];
#pragma unroll
    for (int p = 0; p < 8; ++p) wB[p] = Wb[(size_t)(kk + 1) * 512 + p * 64];
#pragma unroll
    for (int p = 0; p < 8; ++p) {
      acc[p][0] = fmaf(wA[p], hA_.x, acc[p][0]);
      acc[p][1] = fmaf(wA[p], hA_.y, acc[p][1]);
      acc[p][2] = fmaf(wA[p], hA_.z, acc[p][2]);
      acc[p][3] = fmaf(wA[p], hA_.w, acc[p][3]);
    }
    // prefetch kk+2 (last iter over-reads harmlessly; values unused)
    hA_ = src[k0 + kk + 2];
#pragma unroll
    for (int p = 0; p < 8; ++p) wA[p] = Wb[(size_t)(kk + 2) * 512 + p * 64];
#pragma unroll
    for (int p = 0; p < 8; ++p) {
      acc[p][0] = fmaf(wB[p], hB_.x, acc[p][0]);
      acc[p][1] = fmaf(wB[p], hB_.y, acc[p][1]);
      acc[p][2] = fmaf(wB[p], hB_.z, acc[p][2]);
      acc[p][3] = fmaf(wB[p], hB_.w, acc[p][3]);
    }
  }

  // write partials: pa[kh][unit]
#pragma unroll
  for (int p = 0; p < 8; ++p) {
    float4 v;
    v.x = acc[p][0]; v.y = acc[p][1]; v.z = acc[p][2]; v.w = acc[p][3];
    pa[kh][p * 64 + lane] = v;
  }
  __syncthreads();

  // combine: 2 passes, unit u = pass*256 + t
#pragma unroll
  for (int pass = 0; pass < 2; ++pass) {
    const int u = pass * 256 + t;
    const float4 a0 = pa[0][u], a1 = pa[1][u], a2 = pa[2][u], a3 = pa[3][u];
    const float bj = bias[u];
    float a[4];
    a[0] = ((a0.x + a1.x) + (a2.x + a3.x)) + bj;
    a[1] = ((a0.y + a1.y) + (a2.y + a3.y)) + bj;
    a[2] = ((a0.z + a1.z) + (a2.z + a3.z)) + bj;
    a[3] = ((a0.w + a1.w) + (a2.w + a3.w)) + bj;
#pragma unroll
    for (int s = 0; s < 4; ++s) {
      const unsigned long long bal = __ballot(a[s] > 0.f);
      if (lane == 0) {
        uint2 w2;
        w2.x = (uint32_t)bal;
        w2.y = (uint32_t)(bal >> 32);
        *(uint2*)(mbase + (size_t)s * 16 + pass * 8 + 2 * kh) = w2;
      }
    }
    dst[u] = frelu4(a[0], a[1], a[2], a[3]);
  }
  __syncthreads();
}

__global__ __launch_bounds__(256) void forward_kernel(
    const float* __restrict__ x,
    const float* __restrict__ W1Tf, const float* __restrict__ b1,
    const float* __restrict__ W2Tf, const float* __restrict__ b2,
    const float* __restrict__ W3Tf, const float* __restrict__ b3,
    const float* __restrict__ W4Tf, const float* __restrict__ b4,
    uint32_t* __restrict__ m1p, uint32_t* __restrict__ m2p,
    uint32_t* __restrict__ m3p, float* __restrict__ out) {
  // pa declared LAST so k-loop over-prefetch from xs/hU/hV stays in-bounds
  __shared__ float4 xs[64];       // [k] x 4 samples
  __shared__ float4 hU[512];      // [unit] x 4 samples
  __shared__ float4 hV[512];
  __shared__ float4 pa[4][512];   // partials [kh][unit]
  const int t = threadIdx.x;
  const int lane = t & 63, kh = t >> 6;
  const int b0 = blockIdx.x * 4;

  {
    const int k2 = t >> 2, s2 = t & 3;  // 256 threads cover 4 samples x 64 k
    ((float*)&xs[k2])[s2] = x[(size_t)(b0 + s2) * 64 + k2];
  }
  __syncthreads();

  fwd_layer8<16>(W1Tf, b1, xs, hU, pa, m1p + (size_t)b0 * 16, t, lane, kh);
  fwd_layer8<128>(W2Tf, b2, hU, hV, pa, m2p + (size_t)b0 * 16, t, lane, kh);
  fwd_layer8<128>(W3Tf, b3, hV, hU, pa, m3p + (size_t)b0 * 16, t, lane, kh);

  // ---- layer 4 (K=512, D=64) + 0.5*||s||^2 : kh-split, combine in wave 0 ----
  {
    const int d = lane;
    const int k0 = kh * 128;
    const float* Wb = W4Tf + (size_t)k0 * 64 + d;
    float a4[4] = {0.f, 0.f, 0.f, 0.f};
    float wA = Wb[0], wB;
    float4 hA_ = hU[k0], hB_;
#pragma unroll 1
    for (int kk = 0; kk < 128; kk += 2) {
      hB_ = hU[k0 + kk + 1];
      wB = Wb[(size_t)(kk + 1) * 64];
      a4[0] = fmaf(wA, hA_.x, a4[0]); a4[1] = fmaf(wA, hA_.y, a4[1]);
      a4[2] = fmaf(wA, hA_.z, a4[2]); a4[3] = fmaf(wA, hA_.w, a4[3]);
      hA_ = hU[k0 + kk + 2];           // last iter over-reads into hV (unused)
      wA = Wb[(size_t)(kk + 2) * 64];  // last iter over-reads workspace (unused)
      a4[0] = fmaf(wB, hB_.x, a4[0]); a4[1] = fmaf(wB, hB_.y, a4[1]);
      a4[2] = fmaf(wB, hB_.z, a4[2]); a4[3] = fmaf(wB, hB_.w, a4[3]);
    }
    float4 v;
    v.x = a4[0]; v.y = a4[1]; v.z = a4[2]; v.w = a4[3];
    pa[kh][d] = v;
  }
  __syncthreads();
  if (t < 64) {
    const float4 q0 = pa[0][t], q1 = pa[1][t], q2 = pa[2][t], q3 = pa[3][t];
    const float bj = b4[t];
    float sq[4];
    sq[0] = ((q0.x + q1.x) + (q2.x + q3.x)) + bj;
    sq[1] = ((q0.y + q1.y) + (q2.y + q3.y)) + bj;
    sq[2] = ((q0.z + q1.z) + (q2.z + q3.z)) + bj;
    sq[3] = ((q0.w + q1.w) + (q2.w + q3.w)) + bj;
#pragma unroll
    for (int s = 0; s < 4; ++s) sq[s] *= sq[s];
#pragma unroll
    for (int off = 32; off; off >>= 1) {
      sq[0] += __shfl_down(sq[0], off, 64);
      sq[1] += __shfl_down(sq[1], off, 64);
      sq[2] += __shfl_down(sq[2], off, 64);
      sq[3] += __shfl_down(sq[3], off, 64);
    }
    if (t == 0) {
      out[b0 + 0] = 0.5f * sq[0];
      out[b0 + 1] = 0.5f * sq[1];
      out[b0 + 2] = 0.5f * sq[2];
      out[b0 + 3] = 0.5f * sq[3];
    }
  }
}

// ---------------- divergence v5 (R6/R8, 146us): C/G wave split, 4 waves/SIMD ----------------
// grid (512 sample-quads, 8 row-tiles of 64); block 512 = 8 waves.
// Wave wv: sLoc = wv&3 -> sample g4*4+sLoc; role = (wv<4 ? C : G).
// C-wave: accC[4][4] over rows blockIdx.y*64..+64 x cols 0..64 (64 AGPR).
// Staging: per kc, block stages 16 slots (A2 it0-3 | u1 jt0-3 | A3 it0-3 |
// u4 jt0-3); wave wv stages slots wv*2, wv*2+1 (2 global_load_lds). 3 buffers,
// stage kc+2 at top of kc, end-of-kc s_waitcnt vmcnt(2) (kc+1 done, kc+2 in
// flight -- never 0 in steady state) + raw s_barrier.
// Masks: expand_mask hoisted to LDS (emask); in-loop one broadcast b128 per kc.
// Epilogue: C-waves write accC to LDS (stride-65); G-waves apply m2, reduce.
__device__ __forceinline__ void expand_mask(uint32_t byte8, uint32_t mk[4]) {
#pragma unroll
  for (int i = 0; i < 4; ++i) {
    mk[i] = (((byte8 >> (2 * i)) & 1u) ? 0x0000FFFFu : 0u) |
            (((byte8 >> (2 * i + 1)) & 1u) ? 0xFFFF0000u : 0u);
  }
}

__global__ __launch_bounds__(512, 4) void div_kernel(
    const uint4* __restrict__ A2swz, const uint4* __restrict__ A3swz,
    const uint4* __restrict__ B1swz, const uint4* __restrict__ B4swz,
    const uint32_t* __restrict__ m1p, const uint32_t* __restrict__ m2p,
    const uint32_t* __restrict__ m3p, float* __restrict__ out) {
  __shared__ uint4 sfrag[3][16][64];   // 48KB: [buf][slot][lane]
  __shared__ uint4 emask[8][16][4];    // 8KB: [wave][kc][quad] expanded masks
  const int t = threadIdx.x;
  const int lane = t & 63, wv = t >> 6;
  const int quad = lane >> 4, l15 = lane & 15;
  const int g4 = blockIdx.x;
  const int rowB0 = blockIdx.y * 64;
  const int sLoc = wv & 3;
  const int b = g4 * 4 + sLoc;        // this wave's sample
  const int r16b = blockIdx.y * 4;    // row-16-tile base
  const bool isC = (wv < 4);

  // staging source base for this wave's 2 slots
  const uint4* sb = (wv < 2) ? A2swz : (wv < 4) ? B1swz : (wv < 6) ? A3swz : B4swz;

  f32x4 acc[4][4];
#pragma unroll
  for (int it = 0; it < 4; ++it)
#pragma unroll
    for (int jt = 0; jt < 4; ++jt) acc[it][jt] = (f32x4){0.f, 0.f, 0.f, 0.f};

  // per-wave expanded-mask precompute: lane -> (kc = lane>>2, qd = lane&3).
  // C-waves use m1, G-waves use m3. Wave-private (in-wave lgkmcnt ordering).
  {
    const uint32_t* mp = (isC ? m1p : m3p) + (size_t)b * 16;
    const int kcl = lane >> 2, qd = lane & 3;
    const uint32_t word = mp[kcl];
    uint32_t mk[4];
    expand_mask((word >> (qd * 8)) & 0xFFu, mk);
    uint4 v;
    v.x = mk[0]; v.y = mk[1]; v.z = mk[2]; v.w = mk[3];
    emask[wv][kcl][qd] = v;
  }

  // stage(buf, kc): wave wv stages slots wv*2, wv*2+1
  auto stage = [&](int sbuf, int kc) {
#pragma unroll
    for (int q = 0; q < 2; ++q) {
      const int sub = (wv & 1) * 2 + q;  // it or jt index
      const size_t off = ((wv & 2) == 0)
          ? ((size_t)((r16b + sub) * 16 + kc) * 64 + lane)   // A2 / A3
          : ((size_t)(kc * 4 + sub) * 64 + lane);            // B1 / B4
      lds_load16(sb + off, &sfrag[sbuf][wv * 2 + q][0]);
    }
  };

  stage(0, 0);
  stage(1, 1);
  __builtin_amdgcn_sched_barrier(0);
  asm volatile("s_waitcnt vmcnt(2)" ::: "memory");  // kc=0 staging complete
  __builtin_amdgcn_s_barrier();
  __builtin_amdgcn_sched_barrier(0);

  const int base = isC ? 0 : 8;

#pragma unroll 1
  for (int kc = 0; kc < 16; ++kc) {
    const int rb = kc % 3;
    if (kc < 14) stage((kc + 2) % 3, kc + 2);  // keep 2 kc in flight

    const uint4 mku = emask[wv][kc][quad];  // broadcast ds_read_b128

    uint4 a[4], u[4];
#pragma unroll
    for (int q = 0; q < 4; ++q) {
      a[q] = sfrag[rb][base + q][lane];
      u[q] = sfrag[rb][base + 4 + q][lane];
    }

    short8 bf[4];
#pragma unroll
    for (int jt = 0; jt < 4; ++jt) {
      U16x8 uu;
      uu.u = u[jt];
      uu.u.x &= mku.x; uu.u.y &= mku.y; uu.u.z &= mku.z; uu.u.w &= mku.w;
      bf[jt] = uu.s;
    }
#pragma unroll
    for (int it = 0; it < 4; ++it) {
      U16x8 ua;
      ua.u = a[it];
      const short8 af = ua.s;
#pragma unroll
      for (int jt = 0; jt < 4; ++jt)
        acc[it][jt] = __builtin_amdgcn_mfma_f32_16x16x32_bf16(af, bf[jt], acc[it][jt], 0, 0, 0);
    }

    // counted wait: kc+1's staging (oldest 2) done; kc+2's 2 stay in flight.
    if (kc < 14) {
      asm volatile("s_waitcnt vmcnt(2)" ::: "memory");
    } else if (kc == 14) {
      asm volatile("s_waitcnt vmcnt(0)" ::: "memory");  // drain last stage
    }
    if (kc < 15) {
      __builtin_amdgcn_s_barrier();
      __builtin_amdgcn_sched_barrier(0);  // no ds_read hoisting above barrier
    }
  }

  // ---- epilogue: exchange C via LDS (2 halves of 32 rows), G applies m2 ----
  // C/D layout: row = it*16 + quad*4 + reg, col = jt*16 + l15.
  __syncthreads();  // all sfrag reads done; safe to overlay
  float* cxf = (float*)&sfrag[0][0][0];  // [sample][32 rows][stride 65]
  float dsum = 0.f;
  const uint32_t* m2w = m2p + (size_t)b * 16;
#pragma unroll
  for (int h = 0; h < 2; ++h) {
    if (isC) {
#pragma unroll
      for (int ith = 0; ith < 2; ++ith)
#pragma unroll
        for (int jt = 0; jt < 4; ++jt) {
          float* crow = &cxf[((size_t)sLoc * 32 + ith * 16 + quad * 4) * 65 +
                             jt * 16 + l15];
          crow[0 * 65] = acc[h * 2 + ith][jt][0];
          crow[1 * 65] = acc[h * 2 + ith][jt][1];
          crow[2 * 65] = acc[h * 2 + ith][jt][2];
          crow[3 * 65] = acc[h * 2 + ith][jt][3];
        }
    }
    __syncthreads();
    if (!isC) {
#pragma unroll
      for (int ith = 0; ith < 2; ++ith) {
        const int it = h * 2 + ith;
        const int rloc = it * 16 + quad * 4;
        const uint32_t md = m2w[(rowB0 + rloc) >> 5];
        const uint32_t bits = (md >> (rloc & 31)) & 0xFu;
        const float w0 = (bits & 1u) ? 1.f : 0.f;
        const float w1 = (bits & 2u) ? 1.f : 0.f;
        const float w2 = (bits & 4u) ? 1.f : 0.f;
        const float w3 = (bits & 8u) ? 1.f : 0.f;
#pragma unroll
        for (int jt = 0; jt < 4; ++jt) {
          const float* crow = &cxf[((size_t)sLoc * 32 + ith * 16 + quad * 4) * 65 +
                                   jt * 16 + l15];
          dsum = fmaf(w0, acc[it][jt][0] * crow[0 * 65], dsum);
          dsum = fmaf(w1, acc[it][jt][1] * crow[1 * 65], dsum);
          dsum = fmaf(w2, acc[it][jt][2] * crow[2 * 65], dsum);
          dsum = fmaf(w3, acc[it][jt][3] * crow[3 * 65], dsum);
        }
      }
    }
    __syncthreads();
  }
  if (!isC) {
#pragma unroll
    for (int off = 32; off; off >>= 1) dsum += __shfl_down(dsum, off, 64);
    if (lane == 0) atomicAdd(out + b, dsum);
  }
}

extern "C" void kernel_launch(void* const* d_in, const int* in_sizes, int n_in,
                              void* d_out, int out_size, void* d_ws, size_t ws_size,
                              hipStream_t stream) {
  const float* x  = (const float*)d_in[0];
  const float* W1 = (const float*)d_in[1];
  const float* b1 = (const float*)d_in[2];
  const float* W2 = (const float*)d_in[3];
  const float* b2 = (const float*)d_in[4];
  const float* W3 = (const float*)d_in[5];
  const float* b3 = (const float*)d_in[6];
  const float* W4 = (const float*)d_in[7];
  const float* b4 = (const float*)d_in[8];
  float* out = (float*)d_out;

  // workspace layout (bytes), total 3,932,160:
  char* ws = (char*)d_ws;
  uint16_t* A2swz = (uint16_t*)(ws + 0);        // 524288
  uint16_t* A3swz = (uint16_t*)(ws + 524288);   // 524288
  uint16_t* B1swz = (uint16_t*)(ws + 1048576);  // 65536
  uint16_t* B4swz = (uint16_t*)(ws + 1114112);  // 65536
  float*    W2Tf  = (float*)(ws + 1179648);     // 1048576
  float*    W3Tf  = (float*)(ws + 2228224);     // 1048576
  float*    W1Tf  = (float*)(ws + 3276800);     // 131072
  float*    W4Tf  = (float*)(ws + 3407872);     // 131072
  uint32_t* m1p   = (uint32_t*)(ws + 3538944);  // 131072 (2048 x 512 bits)
  uint32_t* m2p   = (uint32_t*)(ws + 3670016);  // 131072
  uint32_t* m3p   = (uint32_t*)(ws + 3801088);  // 131072
  if (ws_size < 3932160) return;

  convert_kernel<<<4608, 256, 0, stream>>>(W1, W2, W3, W4,
                                           A2swz, A3swz, B1swz, B4swz,
                                           W2Tf, W3Tf, W1Tf, W4Tf);
  forward_kernel<<<512, 256, 0, stream>>>(x, W1Tf, b1, W2Tf, b2, W3Tf, b3,
                                          W4Tf, b4, m1p, m2p, m3p, out);
  div_kernel<<<dim3(512, 8), 512, 0, stream>>>((const uint4*)A2swz,
                                               (const uint4*)A3swz,
                                               (const uint4*)B1swz,
                                               (const uint4*)B4swz,
                                               m1p, m2p, m3p, out);
}

// Round 11
// 262.970 us; speedup vs baseline: 1.1785x; 1.0053x over previous
//
#include <hip/hip_runtime.h>
#include <stdint.h>

// ScoreMatching: B=2048, D=64, H=512.
// out[b] = 0.5*||s_b||^2 + tr(W4 M3 W3 M2 W2 M1 W1)_b
// div_b = sum_{i,d} m2[i] * C[i,d] * G[i,d]
//   C = W2 @ (M1 .* W1)      [512 x 64]   A-frag = W2 rows,  B-frag = W1T rows
//   G = W3^T @ (M3 .* W4^T)  [512 x 64]   A-frag = W3T rows, B-frag = W4 rows
// R15 changes:
//  - div: v5 unchanged (147us, reproduced 4x).
//  - forward v9: v5 and v8 each fixed one bottleneck term and regressed
//    another (v5: 4 waves/SIMD but 16x512 broadcast LDS reads/CU; v8: few
//    LDS reads but 2 waves/SIMD + half-iter prefetch). v9 satisfies all
//    three models at once: 512 blocks x 512 thr (8 waves -> 2 blocks/CU ->
//    4 waves/SIMD); wave kh owns a 64-k slice; thread = 8 units x 4 samples
//    (per k: 1 broadcast b128 + 8 coalesced W loads + 32 FMA); 4-deep named
//    W/h register rotation -> reload issued ~48 FMA before use (~400cyc
//    cover at 4 waves/SIMD). Partials: pairwise in-place LDS adds
//    (pah[4][512], 32KB; total LDS 49KB). Mask layout identical to v5/div.
//    Final-prefetch over-reads land in adjacent workspace/LDS (unused).

typedef __attribute__((ext_vector_type(8))) short short8;
typedef __attribute__((ext_vector_type(4))) float f32x4;

union U16x8 {
  uint4 u;
  short8 s;
};

__device__ __forceinline__ uint16_t f2bf(float f) {
  uint32_t u = __float_as_uint(f);
  uint32_t lsb = (u >> 16) & 1u;
  u += 0x7FFFu + lsb;  // round-to-nearest-even
  return (uint16_t)(u >> 16);
}

// async global->LDS, 16B per lane: lane's data lands at lds_base + lane*16.
__device__ __forceinline__ void lds_load16(const uint4* gsrc, uint4* ldst) {
  __builtin_amdgcn_global_load_lds(
      (const __attribute__((address_space(1))) void*)gsrc,
      (__attribute__((address_space(3))) void*)ldst, 16, 0, 0);
}

// ---------------- convert: build swizzled bf16 fragments + fp32 transposes ----------------
// Fragment order (16x16x32 bf16 MFMA): lane = quad*16 + l15 holds 8 contiguous
// bf16 = 16 B; A-frag element (m=l15, k=quad*8+j); B-frag (n=l15, k=quad*8+j).
// A2swz[((r16*16 + kc)*64 + lane)*8 + j] = W2 [r16*16+l15][kc*32+quad*8+j]
// A3swz[  same index                   ] = W3T[r16*16+l15][kc*32+quad*8+j]
// B1swz[((kc*4 + jt)*64 + lane)*8 + j]  = W1T[jt*16+l15 ][kc*32+quad*8+j]
// B4swz[  same index                 ]  = W4 [jt*16+l15 ][kc*32+quad*8+j]
__global__ __launch_bounds__(256) void convert_kernel(
    const float* __restrict__ W1, const float* __restrict__ W2,
    const float* __restrict__ W3, const float* __restrict__ W4,
    uint16_t* __restrict__ A2swz, uint16_t* __restrict__ A3swz,
    uint16_t* __restrict__ B1swz, uint16_t* __restrict__ B4swz,
    float* __restrict__ W2Tf, float* __restrict__ W3Tf,
    float* __restrict__ W1Tf, float* __restrict__ W4Tf) {
  const int i = blockIdx.x * 256 + threadIdx.x;
  if (i < 262144) {  // A2swz
    const int e = i;
    const int f = e >> 3, j = e & 7;
    const int lane = f & 63, fk = f >> 6;
    const int kc = fk & 15, r16 = fk >> 4;
    const int l15 = lane & 15, quad = lane >> 4;
    const int row = r16 * 16 + l15, col = kc * 32 + quad * 8 + j;
    A2swz[e] = f2bf(W2[row * 512 + col]);
  } else if (i < 524288) {  // A3swz (= W3 transposed)
    const int e = i - 262144;
    const int f = e >> 3, j = e & 7;
    const int lane = f & 63, fk = f >> 6;
    const int kc = fk & 15, r16 = fk >> 4;
    const int l15 = lane & 15, quad = lane >> 4;
    const int row = r16 * 16 + l15, col = kc * 32 + quad * 8 + j;
    A3swz[e] = f2bf(W3[col * 512 + row]);
  } else if (i < 557056) {  // B1swz (= W1 transposed)
    const int e = i - 524288;
    const int f = e >> 3, j = e & 7;
    const int lane = f & 63, fk = f >> 6;
    const int kc = fk >> 2, jt = fk & 3;
    const int l15 = lane & 15, quad = lane >> 4;
    const int d = jt * 16 + l15, col = kc * 32 + quad * 8 + j;
    B1swz[e] = f2bf(W1[col * 64 + d]);
  } else if (i < 589824) {  // B4swz (= W4 row-major)
    const int e = i - 557056;
    const int f = e >> 3, j = e & 7;
    const int lane = f & 63, fk = f >> 6;
    const int kc = fk >> 2, jt = fk & 3;
    const int l15 = lane & 15, quad = lane >> 4;
    const int d = jt * 16 + l15, col = kc * 32 + quad * 8 + j;
    B4swz[e] = f2bf(W4[d * 512 + col]);
  } else if (i < 851968) {  // W2Tf [k][j]
    const int e = i - 589824;
    const int k = e >> 9, jj = e & 511;
    W2Tf[e] = W2[jj * 512 + k];
  } else if (i < 1114112) {  // W3Tf [k][j]
    const int e = i - 851968;
    const int k = e >> 9, jj = e & 511;
    W3Tf[e] = W3[jj * 512 + k];
  } else if (i < 1146880) {  // W1Tf [k][j], k<64
    const int e = i - 1114112;
    const int k = e >> 9, jj = e & 511;
    W1Tf[e] = W1[jj * 64 + k];
  } else if (i < 1179648) {  // W4Tf [k][d]
    const int e = i - 1146880;
    const int k = e >> 6, d = e & 63;
    W4Tf[e] = W4[d * 512 + k];
  }
}

// ---------------- forward v9 (fp32): K-sliced waves, 4-deep W rotation ----------------
// 512 blocks x 512 threads (8 waves, 2 blocks/CU -> 4 waves/SIMD);
// block = 4 samples. Wave wv owns k-slice [wv*KPW, (wv+1)*KPW).
// Thread owns units {lane+64p, p=0..7} x 4 samples. Per k: 1 broadcast b128
// (h[k][0..3]) + 8 coalesced w-loads + 32 FMA. w/h rotate through 4 named
// buffers: reload of buffer q issues right after q's FMAs -> ~48 FMA of
// latency cover before next use. Partials combined pairwise in LDS
// (even waves write pah[wv/2], odd waves add), then a 512-thread pass does
// ((q0+q1)+(q2+q3))+bias, ReLU, ballot masks (u=t: wave wv -> words 2wv,2wv+1).
__device__ __forceinline__ void fma8x4(float acc[8][4], const float w[8],
                                       const float4 h) {
#pragma unroll
  for (int p = 0; p < 8; ++p) {
    acc[p][0] = fmaf(w[p], h.x, acc[p][0]);
    acc[p][1] = fmaf(w[p], h.y, acc[p][1]);
    acc[p][2] = fmaf(w[p], h.z, acc[p][2]);
    acc[p][3] = fmaf(w[p], h.w, acc[p][3]);
  }
}

template <int KPW>
__device__ __forceinline__ void fwd_layer9(
    const float* __restrict__ WT, const float* __restrict__ bias,
    const float4* __restrict__ src, float4* __restrict__ dst,
    float4 (* __restrict__ pah)[512], uint32_t* __restrict__ mbase,
    int t, int lane, int wv) {
  float acc[8][4];
#pragma unroll
  for (int p = 0; p < 8; ++p)
#pragma unroll
    for (int s = 0; s < 4; ++s) acc[p][s] = 0.f;

  const int k0 = wv * KPW;
  const float* Wb = WT + (size_t)k0 * 512 + lane;
  float w0[8], w1[8], w2[8], w3[8];
#pragma unroll
  for (int p = 0; p < 8; ++p) {
    w0[p] = Wb[(size_t)0 * 512 + p * 64];
    w1[p] = Wb[(size_t)1 * 512 + p * 64];
    w2[p] = Wb[(size_t)2 * 512 + p * 64];
    w3[p] = Wb[(size_t)3 * 512 + p * 64];
  }
  float4 h0 = src[k0 + 0], h1 = src[k0 + 1], h2 = src[k0 + 2], h3 = src[k0 + 3];

#pragma unroll 1
  for (int kk = 0; kk < KPW; kk += 4) {
    // buffer q: FMA, then immediately issue its reload for kk+4+q
    // (final iteration over-reads into adjacent workspace/LDS; values unused)
    fma8x4(acc, w0, h0);
    h0 = src[k0 + kk + 4];
#pragma unroll
    for (int p = 0; p < 8; ++p) w0[p] = Wb[(size_t)(kk + 4) * 512 + p * 64];
    fma8x4(acc, w1, h1);
    h1 = src[k0 + kk + 5];
#pragma unroll
    for (int p = 0; p < 8; ++p) w1[p] = Wb[(size_t)(kk + 5) * 512 + p * 64];
    fma8x4(acc, w2, h2);
    h2 = src[k0 + kk + 6];
#pragma unroll
    for (int p = 0; p < 8; ++p) w2[p] = Wb[(size_t)(kk + 6) * 512 + p * 64];
    fma8x4(acc, w3, h3);
    h3 = src[k0 + kk + 7];
#pragma unroll
    for (int p = 0; p < 8; ++p) w3[p] = Wb[(size_t)(kk + 7) * 512 + p * 64];
  }

  // pairwise partial combine: even waves write, odd waves add (deterministic)
  const int half = wv >> 1;
  if ((wv & 1) == 0) {
#pragma unroll
    for (int p = 0; p < 8; ++p) {
      float4 v;
      v.x = acc[p][0]; v.y = acc[p][1]; v.z = acc[p][2]; v.w = acc[p][3];
      pah[half][p * 64 + lane] = v;
    }
  }
  __syncthreads();
  if (wv & 1) {
#pragma unroll
    for (int p = 0; p < 8; ++p) {
      float4 v = pah[half][p * 64 + lane];
      v.x += acc[p][0]; v.y += acc[p][1]; v.z += acc[p][2]; v.w += acc[p][3];
      pah[half][p * 64 + lane] = v;
    }
  }
  __syncthreads();

  // combine pass: unit u = t
  {
    const int u = t;
    const float4 a0 = pah[0][u], a1 = pah[1][u], a2 = pah[2][u], a3 = pah[3][u];
    const float bj = bias[u];
    float a[4];
    a[0] = ((a0.x + a1.x) + (a2.x + a3.x)) + bj;
    a[1] = ((a0.y + a1.y) + (a2.y + a3.y)) + bj;
    a[2] = ((a0.z + a1.z) + (a2.z + a3.z)) + bj;
    a[3] = ((a0.w + a1.w) + (a2.w + a3.w)) + bj;
#pragma unroll
    for (int s = 0; s < 4; ++s) {
      const unsigned long long bal = __ballot(a[s] > 0.f);
      if (lane == 0) {
        uint2 w2v;
        w2v.x = (uint32_t)bal;
        w2v.y = (uint32_t)(bal >> 32);
        *(uint2*)(mbase + (size_t)s * 16 + 2 * wv) = w2v;
      }
    }
    float4 r;
    r.x = a[0] > 0.f ? a[0] : 0.f;
    r.y = a[1] > 0.f ? a[1] : 0.f;
    r.z = a[2] > 0.f ? a[2] : 0.f;
    r.w = a[3] > 0.f ? a[3] : 0.f;
    dst[u] = r;
  }
  __syncthreads();
}

__global__ __launch_bounds__(512, 4) void forward_kernel(
    const float* __restrict__ x,
    const float* __restrict__ W1Tf, const float* __restrict__ b1,
    const float* __restrict__ W2Tf, const float* __restrict__ b2,
    const float* __restrict__ W3Tf, const float* __restrict__ b3,
    const float* __restrict__ W4Tf, const float* __restrict__ b4,
    uint32_t* __restrict__ m1p, uint32_t* __restrict__ m2p,
    uint32_t* __restrict__ m3p, float* __restrict__ out) {
  // pah declared LAST so k-loop over-prefetch from xs/hU/hV stays in-bounds
  __shared__ float4 xs[64];      // [k] x 4 samples
  __shared__ float4 hU[512];     // [unit] x 4 samples
  __shared__ float4 hV[512];
  __shared__ float4 pah[4][512]; // pairwise partials
  const int t = threadIdx.x;
  const int lane = t & 63, wv = t >> 6;
  const int b0 = blockIdx.x * 4;

  if (t < 256) {
    const int k2 = t >> 2, s2 = t & 3;  // 256 threads cover 4 samples x 64 k
    ((float*)&xs[k2])[s2] = x[(size_t)(b0 + s2) * 64 + k2];
  }
  __syncthreads();

  fwd_layer9<8>(W1Tf, b1, xs, hU, pah, m1p + (size_t)b0 * 16, t, lane, wv);
  fwd_layer9<64>(W2Tf, b2, hU, hV, pah, m2p + (size_t)b0 * 16, t, lane, wv);
  fwd_layer9<64>(W3Tf, b3, hV, hU, pah, m3p + (size_t)b0 * 16, t, lane, wv);

  // ---- layer 4 (K=512, D=64) + 0.5*||s||^2 : wave wv owns 64-k slice ----
  {
    const int d = lane;
    const int k0 = wv * 64;
    const float* Wb4 = W4Tf + (size_t)k0 * 64 + d;
    float a4[4] = {0.f, 0.f, 0.f, 0.f};
    float v0 = Wb4[(size_t)0 * 64], v1 = Wb4[(size_t)1 * 64];
    float v2 = Wb4[(size_t)2 * 64], v3 = Wb4[(size_t)3 * 64];
    float4 g0 = hU[k0 + 0], g1 = hU[k0 + 1], g2 = hU[k0 + 2], g3 = hU[k0 + 3];
#pragma unroll 1
    for (int kk = 0; kk < 64; kk += 4) {
      a4[0] = fmaf(v0, g0.x, a4[0]); a4[1] = fmaf(v0, g0.y, a4[1]);
      a4[2] = fmaf(v0, g0.z, a4[2]); a4[3] = fmaf(v0, g0.w, a4[3]);
      g0 = hU[k0 + kk + 4];
      v0 = Wb4[(size_t)(kk + 4) * 64];
      a4[0] = fmaf(v1, g1.x, a4[0]); a4[1] = fmaf(v1, g1.y, a4[1]);
      a4[2] = fmaf(v1, g1.z, a4[2]); a4[3] = fmaf(v1, g1.w, a4[3]);
      g1 = hU[k0 + kk + 5];
      v1 = Wb4[(size_t)(kk + 5) * 64];
      a4[0] = fmaf(v2, g2.x, a4[0]); a4[1] = fmaf(v2, g2.y, a4[1]);
      a4[2] = fmaf(v2, g2.z, a4[2]); a4[3] = fmaf(v2, g2.w, a4[3]);
      g2 = hU[k0 + kk + 6];
      v2 = Wb4[(size_t)(kk + 6) * 64];
      a4[0] = fmaf(v3, g3.x, a4[0]); a4[1] = fmaf(v3, g3.y, a4[1]);
      a4[2] = fmaf(v3, g3.z, a4[2]); a4[3] = fmaf(v3, g3.w, a4[3]);
      g3 = hU[k0 + kk + 7];
      v3 = Wb4[(size_t)(kk + 7) * 64];
    }
    const int half = wv >> 1;
    float4 pv;
    pv.x = a4[0]; pv.y = a4[1]; pv.z = a4[2]; pv.w = a4[3];
    if ((wv & 1) == 0) pah[half][d] = pv;
    __syncthreads();
    if (wv & 1) {
      float4 v = pah[half][d];
      v.x += pv.x; v.y += pv.y; v.z += pv.z; v.w += pv.w;
      pah[half][d] = v;
    }
    __syncthreads();
  }
  if (t < 64) {
    const float4 q0 = pah[0][t], q1 = pah[1][t], q2 = pah[2][t], q3 = pah[3][t];
    const float bj = b4[t];
    float sq[4];
    sq[0] = ((q0.x + q1.x) + (q2.x + q3.x)) + bj;
    sq[1] = ((q0.y + q1.y) + (q2.y + q3.y)) + bj;
    sq[2] = ((q0.z + q1.z) + (q2.z + q3.z)) + bj;
    sq[3] = ((q0.w + q1.w) + (q2.w + q3.w)) + bj;
#pragma unroll
    for (int s = 0; s < 4; ++s) sq[s] *= sq[s];
#pragma unroll
    for (int off = 32; off; off >>= 1) {
      sq[0] += __shfl_down(sq[0], off, 64);
      sq[1] += __shfl_down(sq[1], off, 64);
      sq[2] += __shfl_down(sq[2], off, 64);
      sq[3] += __shfl_down(sq[3], off, 64);
    }
    if (t == 0) {
      out[b0 + 0] = 0.5f * sq[0];
      out[b0 + 1] = 0.5f * sq[1];
      out[b0 + 2] = 0.5f * sq[2];
      out[b0 + 3] = 0.5f * sq[3];
    }
  }
}

// ---------------- divergence v5 (R6/R8, ~147us): C/G wave split, 4 waves/SIMD ----------------
// grid (512 sample-quads, 8 row-tiles of 64); block 512 = 8 waves.
// Wave wv: sLoc = wv&3 -> sample g4*4+sLoc; role = (wv<4 ? C : G).
// C-wave: accC[4][4] over rows blockIdx.y*64..+64 x cols 0..64 (64 AGPR).
// Staging: per kc, block stages 16 slots (A2 it0-3 | u1 jt0-3 | A3 it0-3 |
// u4 jt0-3); wave wv stages slots wv*2, wv*2+1 (2 global_load_lds). 3 buffers,
// stage kc+2 at top of kc, end-of-kc s_waitcnt vmcnt(2) (kc+1 done, kc+2 in
// flight -- never 0 in steady state) + raw s_barrier.
// Masks: expand_mask hoisted to LDS (emask); in-loop one broadcast b128 per kc.
// Epilogue: C-waves write accC to LDS (stride-65); G-waves apply m2, reduce.
__device__ __forceinline__ void expand_mask(uint32_t byte8, uint32_t mk[4]) {
#pragma unroll
  for (int i = 0; i < 4; ++i) {
    mk[i] = (((byte8 >> (2 * i)) & 1u) ? 0x0000FFFFu : 0u) |
            (((byte8 >> (2 * i + 1)) & 1u) ? 0xFFFF0000u : 0u);
  }
}

__global__ __launch_bounds__(512, 4) void div_kernel(
    const uint4* __restrict__ A2swz, const uint4* __restrict__ A3swz,
    const uint4* __restrict__ B1swz, const uint4* __restrict__ B4swz,
    const uint32_t* __restrict__ m1p, const uint32_t* __restrict__ m2p,
    const uint32_t* __restrict__ m3p, float* __restrict__ out) {
  __shared__ uint4 sfrag[3][16][64];   // 48KB: [buf][slot][lane]
  __shared__ uint4 emask[8][16][4];    // 8KB: [wave][kc][quad] expanded masks
  const int t = threadIdx.x;
  const int lane = t & 63, wv = t >> 6;
  const int quad = lane >> 4, l15 = lane & 15;
  const int g4 = blockIdx.x;
  const int rowB0 = blockIdx.y * 64;
  const int sLoc = wv & 3;
  const int b = g4 * 4 + sLoc;        // this wave's sample
  const int r16b = blockIdx.y * 4;    // row-16-tile base
  const bool isC = (wv < 4);

  // staging source base for this wave's 2 slots
  const uint4* sb = (wv < 2) ? A2swz : (wv < 4) ? B1swz : (wv < 6) ? A3swz : B4swz;

  f32x4 acc[4][4];
#pragma unroll
  for (int it = 0; it < 4; ++it)
#pragma unroll
    for (int jt = 0; jt < 4; ++jt) acc[it][jt] = (f32x4){0.f, 0.f, 0.f, 0.f};

  // per-wave expanded-mask precompute: lane -> (kc = lane>>2, qd = lane&3).
  // C-waves use m1, G-waves use m3. Wave-private (in-wave lgkmcnt ordering).
  {
    const uint32_t* mp = (isC ? m1p : m3p) + (size_t)b * 16;
    const int kcl = lane >> 2, qd = lane & 3;
    const uint32_t word = mp[kcl];
    uint32_t mk[4];
    expand_mask((word >> (qd * 8)) & 0xFFu, mk);
    uint4 v;
    v.x = mk[0]; v.y = mk[1]; v.z = mk[2]; v.w = mk[3];
    emask[wv][kcl][qd] = v;
  }

  // stage(buf, kc): wave wv stages slots wv*2, wv*2+1
  auto stage = [&](int sbuf, int kc) {
#pragma unroll
    for (int q = 0; q < 2; ++q) {
      const int sub = (wv & 1) * 2 + q;  // it or jt index
      const size_t off = ((wv & 2) == 0)
          ? ((size_t)((r16b + sub) * 16 + kc) * 64 + lane)   // A2 / A3
          : ((size_t)(kc * 4 + sub) * 64 + lane);            // B1 / B4
      lds_load16(sb + off, &sfrag[sbuf][wv * 2 + q][0]);
    }
  };

  stage(0, 0);
  stage(1, 1);
  __builtin_amdgcn_sched_barrier(0);
  asm volatile("s_waitcnt vmcnt(2)" ::: "memory");  // kc=0 staging complete
  __builtin_amdgcn_s_barrier();
  __builtin_amdgcn_sched_barrier(0);

  const int base = isC ? 0 : 8;

#pragma unroll 1
  for (int kc = 0; kc < 16; ++kc) {
    const int rb = kc % 3;
    if (kc < 14) stage((kc + 2) % 3, kc + 2);  // keep 2 kc in flight

    const uint4 mku = emask[wv][kc][quad];  // broadcast ds_read_b128

    uint4 a[4], u[4];
#pragma unroll
    for (int q = 0; q < 4; ++q) {
      a[q] = sfrag[rb][base + q][lane];
      u[q] = sfrag[rb][base + 4 + q][lane];
    }

    short8 bf[4];
#pragma unroll
    for (int jt = 0; jt < 4; ++jt) {
      U16x8 uu;
      uu.u = u[jt];
      uu.u.x &= mku.x; uu.u.y &= mku.y; uu.u.z &= mku.z; uu.u.w &= mku.w;
      bf[jt] = uu.s;
    }
#pragma unroll
    for (int it = 0; it < 4; ++it) {
      U16x8 ua;
      ua.u = a[it];
      const short8 af = ua.s;
#pragma unroll
      for (int jt = 0; jt < 4; ++jt)
        acc[it][jt] = __builtin_amdgcn_mfma_f32_16x16x32_bf16(af, bf[jt], acc[it][jt], 0, 0, 0);
    }

    // counted wait: kc+1's staging (oldest 2) done; kc+2's 2 stay in flight.
    if (kc < 14) {
      asm volatile("s_waitcnt vmcnt(2)" ::: "memory");
    } else if (kc == 14) {
      asm volatile("s_waitcnt vmcnt(0)" ::: "memory");  // drain last stage
    }
    if (kc < 15) {
      __builtin_amdgcn_s_barrier();
      __builtin_amdgcn_sched_barrier(0);  // no ds_read hoisting above barrier
    }
  }

  // ---- epilogue: exchange C via LDS (2 halves of 32 rows), G applies m2 ----
  // C/D layout: row = it*16 + quad*4 + reg, col = jt*16 + l15.
  __syncthreads();  // all sfrag reads done; safe to overlay
  float* cxf = (float*)&sfrag[0][0][0];  // [sample][32 rows][stride 65]
  float dsum = 0.f;
  const uint32_t* m2w = m2p + (size_t)b * 16;
#pragma unroll
  for (int h = 0; h < 2; ++h) {
    if (isC) {
#pragma unroll
      for (int ith = 0; ith < 2; ++ith)
#pragma unroll
        for (int jt = 0; jt < 4; ++jt) {
          float* crow = &cxf[((size_t)sLoc * 32 + ith * 16 + quad * 4) * 65 +
                             jt * 16 + l15];
          crow[0 * 65] = acc[h * 2 + ith][jt][0];
          crow[1 * 65] = acc[h * 2 + ith][jt][1];
          crow[2 * 65] = acc[h * 2 + ith][jt][2];
          crow[3 * 65] = acc[h * 2 + ith][jt][3];
        }
    }
    __syncthreads();
    if (!isC) {
#pragma unroll
      for (int ith = 0; ith < 2; ++ith) {
        const int it = h * 2 + ith;
        const int rloc = it * 16 + quad * 4;
        const uint32_t md = m2w[(rowB0 + rloc) >> 5];
        const uint32_t bits = (md >> (rloc & 31)) & 0xFu;
        const float w0 = (bits & 1u) ? 1.f : 0.f;
        const float w1 = (bits & 2u) ? 1.f : 0.f;
        const float w2 = (bits & 4u) ? 1.f : 0.f;
        const float w3 = (bits & 8u) ? 1.f : 0.f;
#pragma unroll
        for (int jt = 0; jt < 4; ++jt) {
          const float* crow = &cxf[((size_t)sLoc * 32 + ith * 16 + quad * 4) * 65 +
                                   jt * 16 + l15];
          dsum = fmaf(w0, acc[it][jt][0] * crow[0 * 65], dsum);
          dsum = fmaf(w1, acc[it][jt][1] * crow[1 * 65], dsum);
          dsum = fmaf(w2, acc[it][jt][2] * crow[2 * 65], dsum);
          dsum = fmaf(w3, acc[it][jt][3] * crow[3 * 65], dsum);
        }
      }
    }
    __syncthreads();
  }
  if (!isC) {
#pragma unroll
    for (int off = 32; off; off >>= 1) dsum += __shfl_down(dsum, off, 64);
    if (lane == 0) atomicAdd(out + b, dsum);
  }
}

extern "C" void kernel_launch(void* const* d_in, const int* in_sizes, int n_in,
                              void* d_out, int out_size, void* d_ws, size_t ws_size,
                              hipStream_t stream) {
  const float* x  = (const float*)d_in[0];
  const float* W1 = (const float*)d_in[1];
  const float* b1 = (const float*)d_in[2];
  const float* W2 = (const float*)d_in[3];
  const float* b2 = (const float*)d_in[4];
  const float* W3 = (const float*)d_in[5];
  const float* b3 = (const float*)d_in[6];
  const float* W4 = (const float*)d_in[7];
  const float* b4 = (const float*)d_in[8];
  float* out = (float*)d_out;

  // workspace layout (bytes), total 3,932,160:
  char* ws = (char*)d_ws;
  uint16_t* A2swz = (uint16_t*)(ws + 0);        // 524288
  uint16_t* A3swz = (uint16_t*)(ws + 524288);   // 524288
  uint16_t* B1swz = (uint16_t*)(ws + 1048576);  // 65536
  uint16_t* B4swz = (uint16_t*)(ws + 1114112);  // 65536
  float*    W2Tf  = (float*)(ws + 1179648);     // 1048576
  float*    W3Tf  = (float*)(ws + 2228224);     // 1048576
  float*    W1Tf  = (float*)(ws + 3276800);     // 131072
  float*    W4Tf  = (float*)(ws + 3407872);     // 131072
  uint32_t* m1p   = (uint32_t*)(ws + 3538944);  // 131072 (2048 x 512 bits)
  uint32_t* m2p   = (uint32_t*)(ws + 3670016);  // 131072
  uint32_t* m3p   = (uint32_t*)(ws + 3801088);  // 131072
  if (ws_size < 3932160) return;

  convert_kernel<<<4608, 256, 0, stream>>>(W1, W2, W3, W4,
                                           A2swz, A3swz, B1swz, B4swz,
                                           W2Tf, W3Tf, W1Tf, W4Tf);
  forward_kernel<<<512, 512, 0, stream>>>(x, W1Tf, b1, W2Tf, b2, W3Tf, b3,
                                          W4Tf, b4, m1p, m2p, m3p, out);
  div_kernel<<<dim3(512, 8), 512, 0, stream>>>((const uint4*)A2swz,
                                               (const uint4*)A3swz,
                                               (const uint4*)B1swz,
                                               (const uint4*)B4swz,
                                               m1p, m2p, m3p, out);
}